// Round 1
// baseline (342.842 us; speedup 1.0000x reference)
//
#include <hip/hip_runtime.h>

typedef __bf16 bf16x8 __attribute__((ext_vector_type(8)));
typedef float f32x4 __attribute__((ext_vector_type(4)));

// ---------------------------------------------------------------------------
// Workspace layout (bytes):
#define OFF_BSF   0x000000   // f32  [4][256][1024]  4 MB
#define OFF_BSFT  0x400000   // bf16 [4][1024][256]  2 MB   (spatial-major)
#define OFF_BSFB  0x600000   // bf16 [4][256][1024]  2 MB   (channel-major)
#define OFF_Z     0x800000   // f32  [4][256][1024]  4 MB
#define OFF_SBH   0xC00000   // bf16 [4][256][256]   512 KB  S hi
#define OFF_SBL   0xC80000   // bf16 [4][256][256]   512 KB  S lo (residual)
#define OFF_T0    0xD00000   // bf16 [4][256][256]   T0 = U*S
#define OFF_MTH   0xD80000   // bf16 [4][256][256]   Mth
#define OFF_OWB   0xE00000   // bf16 [256][256]
#define OFF_GWT   0xE20000   // bf16 g_w^T
#define OFF_PHT   0xE40000   // bf16 ph_w^T
#define OFF_THT   0xE60000   // bf16 th_w^T
#define OFF_UB    0xE80000   // bf16 U = ow*g_w
#define OFF_VB    0xEA0000   // bf16 V = ph_w^T*th_w
#define OFF_VTB   0xEC0000   // bf16 V^T
#define OFF_RPART 0xEE0000   // f32 [16][1024] row-sum partials
#define OFF_R     0xEF0000   // f32 [4][256]  r = bsf.1
#define OFF_UV    0xEF1000   // f32 [256]  u = ow*g_b
#define OFF_V2    0xEF1400   // f32 [256]  v2 = ph_w^T*th_b
#define OFF_W2    0xEF1800   // f32 [256]  w2 = th_w^T*ph_b
#define OFF_S2    0xEF1C00   // f32 s2 = ph_b.th_b
#define OFF_RV2   0xEF1C40   // f32 [4]  r.v2
#define OFF_CVEC  0xEF2000   // f32 [4][256]  U*r
#define OFF_GVEC  0xEF3000   // f32 [4][256]  (V^T r)/N + w2
#define OFF_QV    0xEF4000   // f32 [4][256]  per-channel constant of z
#define OFF_PGN   0xEF5000   // f32 [4][4][16][8][2] GN partials  16 KB
#define OFF_STATS 0xEF9000   // f32 [4][32][2] (mean, inv)
#define OFF_BAR   0xEF9400   // u32 [8] grid-barrier counters
// ---------------------------------------------------------------------------

// ---------------- prep: gather + weight cvt/transpose + bias matvecs --------
__global__ __launch_bounds__(256) void prep_k(
    const float* __restrict__ f0, const float* __restrict__ f1,
    const float* __restrict__ f2, const float* __restrict__ f3,
    const float* __restrict__ f4,
    const float* __restrict__ g_w, const float* __restrict__ ph_w,
    const float* __restrict__ th_w, const float* __restrict__ ow_w,
    const float* __restrict__ g_b, const float* __restrict__ ph_b,
    const float* __restrict__ th_b,
    char* __restrict__ ws)
{
  const int blk = blockIdx.x, t = threadIdx.x;
  __shared__ __attribute__((aligned(16))) union {
    __bf16 Lt[64][66];
    __bf16 T[64][72];
    float vec[256];
  } sm;

  if (blk < 256) {
    // ---- gather: bsf fp32 + bsfB bf16 (ch-major) + bsfT bf16 (sp-major) + rowsum partials
    float*  bsf   = (float*)(ws + OFF_BSF);
    __bf16* bsfT  = (__bf16*)(ws + OFF_BSFT);
    __bf16* bsfB  = (__bf16*)(ws + OFF_BSFB);
    float*  rpart = (float*)(ws + OFF_RPART);
    const int sblk = blk & 15, cblk = (blk >> 4) & 3, b = blk >> 6;
    const int c0 = cblk * 64, s0 = sblk * 64;
    const int spl = t & 63, sp = s0 + spl;
    const int y = sp >> 5, x = sp & 31;
#pragma unroll
    for (int i = 0; i < 16; ++i) {
      const int cl = (t >> 6) + i * 4;
      const int nc = b * 256 + c0 + cl;

      const float* p0 = f0 + (size_t)nc * 16384 + (y * 4) * 128 + x * 4;
      float4 r0 = *(const float4*)(p0);
      float4 r1 = *(const float4*)(p0 + 128);
      float4 r2 = *(const float4*)(p0 + 256);
      float4 r3 = *(const float4*)(p0 + 384);
      float a  = fmaxf(fmaxf(r0.x, r0.y), fmaxf(r0.z, r0.w));
      float bb = fmaxf(fmaxf(r1.x, r1.y), fmaxf(r1.z, r1.w));
      float c  = fmaxf(fmaxf(r2.x, r2.y), fmaxf(r2.z, r2.w));
      float d  = fmaxf(fmaxf(r3.x, r3.y), fmaxf(r3.z, r3.w));
      float m0v = fmaxf(fmaxf(a, bb), fmaxf(c, d));

      const float* p1 = f1 + (size_t)nc * 4096 + (y * 2) * 64 + x * 2;
      float2 s0v = *(const float2*)(p1);
      float2 s1v = *(const float2*)(p1 + 64);
      float m1v = fmaxf(fmaxf(s0v.x, s0v.y), fmaxf(s1v.x, s1v.y));

      float v2 = f2[(size_t)nc * 1024 + sp];
      float v3 = f3[(size_t)nc * 256 + (y >> 1) * 16 + (x >> 1)];
      float v4 = f4[(size_t)nc * 64  + (y >> 2) * 8  + (x >> 2)];
      float val = (m0v + m1v + v2 + v3 + v4) * 0.2f;
      bsf[(size_t)nc * 1024 + sp]  = val;
      bsfB[(size_t)nc * 1024 + sp] = (__bf16)val;
      sm.Lt[cl][spl] = (__bf16)val;
      float rs = val;
#pragma unroll
      for (int off = 32; off; off >>= 1) rs += __shfl_down(rs, off);
      if (spl == 0) rpart[sblk * 1024 + nc] = rs;
    }
    __syncthreads();
#pragma unroll
    for (int i = 0; i < 16; ++i) {
      int linear = t + i * 256;
      int spl2 = linear >> 6, cl2 = linear & 63;
      bsfT[((size_t)b * 1024 + s0 + spl2) * 256 + c0 + cl2] = sm.Lt[cl2][spl2];
    }
  } else if (blk < 304) {
    // ---- weight transposes (fp32 -> bf16): gwT/phT/thT, 64x64 tiles
    const int w = (blk - 256) >> 4, tl = (blk - 256) & 15;
    const float* src = (w == 0) ? g_w : (w == 1) ? ph_w : th_w;
    __bf16* dst = (__bf16*)(ws + ((w == 0) ? OFF_GWT : (w == 1) ? OFF_PHT : OFF_THT));
    const int ti = (tl >> 2) * 64, tj = (tl & 3) * 64;
#pragma unroll
    for (int i = 0; i < 4; ++i) {
      int idx = i * 256 + t;
      int r = idx >> 4, c4 = (idx & 15) << 2;
      float4 v = *(const float4*)&src[(size_t)(ti + r) * 256 + tj + c4];
      sm.T[c4 + 0][r] = (__bf16)v.x;
      sm.T[c4 + 1][r] = (__bf16)v.y;
      sm.T[c4 + 2][r] = (__bf16)v.z;
      sm.T[c4 + 3][r] = (__bf16)v.w;
    }
    __syncthreads();
#pragma unroll
    for (int i = 0; i < 2; ++i) {
      int idx = i * 256 + t;
      int aa = idx >> 3, cc = (idx & 7) << 3;
      bf16x8 o = *(const bf16x8*)&sm.T[aa][cc];
      *(bf16x8*)&dst[(size_t)(tj + aa) * 256 + ti + cc] = o;
    }
  } else if (blk < 308) {
    // ---- owB plain convert
    const int r0 = (blk - 304) * 64;
    __bf16* owB = (__bf16*)(ws + OFF_OWB);
#pragma unroll
    for (int i = 0; i < 8; ++i) {
      int lin = i * 2048 + t * 8;
      size_t gidx = (size_t)r0 * 256 + lin;
      float4 v0 = *(const float4*)&ow_w[gidx];
      float4 v1 = *(const float4*)&ow_w[gidx + 4];
      bf16x8 o;
      o[0] = (__bf16)v0.x; o[1] = (__bf16)v0.y; o[2] = (__bf16)v0.z; o[3] = (__bf16)v0.w;
      o[4] = (__bf16)v1.x; o[5] = (__bf16)v1.y; o[6] = (__bf16)v1.z; o[7] = (__bf16)v1.w;
      *(bf16x8*)&owB[gidx] = o;
    }
  } else if (blk == 308) {
    // ---- u = ow_w . g_b  (wave-per-row dots) ; zero grid-barrier counters
    float* uv = (float*)(ws + OFF_UV);
    unsigned* bar = (unsigned*)(ws + OFF_BAR);
    sm.vec[t] = g_b[t];
    __syncthreads();
    const int wv = t >> 6, l = t & 63;
    for (int rr = 0; rr < 64; ++rr) {
      int row = wv * 64 + rr;
      const float* p = ow_w + (size_t)row * 256;
      float pa = p[l] * sm.vec[l] + p[64 + l] * sm.vec[64 + l]
               + p[128 + l] * sm.vec[128 + l] + p[192 + l] * sm.vec[192 + l];
#pragma unroll
      for (int off = 32; off; off >>= 1) pa += __shfl_down(pa, off);
      if (l == 0) uv[row] = pa;
    }
    if (t < 8) bar[t] = 0u;
  } else if (blk == 309) {
    // ---- v2 = ph_w^T . th_b (column dot, coalesced) ; s2 = ph_b.th_b
    float* v2 = (float*)(ws + OFF_V2);
    float* s2 = (float*)(ws + OFF_S2);
    float acc = 0.f;
#pragma unroll 8
    for (int c = 0; c < 256; ++c) acc += ph_w[(size_t)c * 256 + t] * th_b[c];
    v2[t] = acc;
    if (t < 64) {
      float pa = ph_b[t] * th_b[t] + ph_b[64 + t] * th_b[64 + t]
               + ph_b[128 + t] * th_b[128 + t] + ph_b[192 + t] * th_b[192 + t];
#pragma unroll
      for (int off = 32; off; off >>= 1) pa += __shfl_down(pa, off);
      if (t == 0) s2[0] = pa;
    }
  } else {
    // ---- w2 = th_w^T . ph_b
    float* w2 = (float*)(ws + OFF_W2);
    float acc = 0.f;
#pragma unroll 8
    for (int c = 0; c < 256; ++c) acc += th_w[(size_t)c * 256 + t] * ph_b[c];
    w2[t] = acc;
  }
}

// ---------------- GEMM accumulate core (64x64 tile, 4 waves, dbuf) ----------
__device__ __forceinline__ void gemm_acc(
    const __bf16* __restrict__ A, const __bf16* __restrict__ B,
    const int K, const int m0, const int n0,
    __bf16 (*Al)[64][72], __bf16 (*Bl)[64][72],
    f32x4 acc[2][2])
{
  const int t = threadIdx.x;
  const int lane = t & 63, wv = t >> 6;
  const int wm = (wv & 1) * 32, wn = (wv >> 1) * 32;
  const int fr = lane & 15, lk = (lane >> 4) * 8;
  const int sr = t >> 2, sk = (t & 3) * 16;

  const __bf16* Ar = A + (size_t)(m0 + sr) * K + sk;
  const __bf16* Br = B + (size_t)(n0 + sr) * K + sk;

  bf16x8 ra0 = *(const bf16x8*)(Ar);
  bf16x8 ra1 = *(const bf16x8*)(Ar + 8);
  bf16x8 rb0 = *(const bf16x8*)(Br);
  bf16x8 rb1 = *(const bf16x8*)(Br + 8);

  const int nIter = K >> 6;
  int p = 0;
  for (int it = 0; it < nIter; ++it) {
    *(bf16x8*)&Al[p][sr][sk]     = ra0;
    *(bf16x8*)&Al[p][sr][sk + 8] = ra1;
    *(bf16x8*)&Bl[p][sr][sk]     = rb0;
    *(bf16x8*)&Bl[p][sr][sk + 8] = rb1;
    __syncthreads();
    if (it + 1 < nIter) {
      const __bf16* An = Ar + (size_t)(it + 1) * 64;
      const __bf16* Bn = Br + (size_t)(it + 1) * 64;
      ra0 = *(const bf16x8*)(An);
      ra1 = *(const bf16x8*)(An + 8);
      rb0 = *(const bf16x8*)(Bn);
      rb1 = *(const bf16x8*)(Bn + 8);
    }
#pragma unroll
    for (int kk = 0; kk < 64; kk += 32) {
      bf16x8 a0 = *(const bf16x8*)&Al[p][wm + fr][kk + lk];
      bf16x8 a1 = *(const bf16x8*)&Al[p][wm + 16 + fr][kk + lk];
      bf16x8 b0 = *(const bf16x8*)&Bl[p][wn + fr][kk + lk];
      bf16x8 b1 = *(const bf16x8*)&Bl[p][wn + 16 + fr][kk + lk];
      acc[0][0] = __builtin_amdgcn_mfma_f32_16x16x32_bf16(a0, b0, acc[0][0], 0, 0, 0);
      acc[0][1] = __builtin_amdgcn_mfma_f32_16x16x32_bf16(a0, b1, acc[0][1], 0, 0, 0);
      acc[1][0] = __builtin_amdgcn_mfma_f32_16x16x32_bf16(a1, b0, acc[1][0], 0, 0, 0);
      acc[1][1] = __builtin_amdgcn_mfma_f32_16x16x32_bf16(a1, b1, acc[1][1], 0, 0, 0);
    }
    __syncthreads();
    p ^= 1;
  }
}

__device__ __forceinline__ void store_bf16(
    __bf16* dst, int ldst, const f32x4 acc[2][2],
    int m0, int n0, int wm, int wn, int rbase, int fr)
{
#pragma unroll
  for (int i = 0; i < 2; ++i)
#pragma unroll
    for (int r = 0; r < 4; ++r) {
      int m = m0 + wm + i * 16 + rbase + r;
#pragma unroll
      for (int j = 0; j < 2; ++j) {
        int n = n0 + wn + j * 16 + fr;
        dst[(size_t)m * ldst + n] = (__bf16)acc[i][j][r];
      }
    }
}

// ---------------- software grid barrier (all 256 blocks co-resident) --------
__device__ __forceinline__ void gsync(unsigned* c, unsigned nb)
{
  __syncthreads();
  __threadfence();
  if (threadIdx.x == 0) atomicAdd(c, 1u);
  while (__hip_atomic_load(c, __ATOMIC_RELAXED, __HIP_MEMORY_SCOPE_AGENT) < nb)
    __builtin_amdgcn_s_sleep(2);
  __threadfence();
  __syncthreads();
}

// ---------------- persistent middle kernel ----------------------------------
// P0: S = bsf.bsf^T (hi/lo bf16) ; U = ow*g_w ; V = ph_w^T*th_w ; r finalize
// P1: T0 = U*S (split-compensated) ; cvec = U*r ; gvec = (V^T r)/N + w2 ; rv2
// P2: Mth = T0*V/N + rank-1 bias terms ; qv = per-channel const of z
// P3: z = Mth*bsf + qv  (+ GN partial stats)
// P4: GN stats finalize
__global__ __launch_bounds__(256) void middle_k(char* __restrict__ ws,
                                                const float* __restrict__ ow_b)
{
  const int blk = blockIdx.x, t = threadIdx.x;
  __shared__ __attribute__((aligned(16))) __bf16 Al[2][64][72];
  __shared__ __attribute__((aligned(16))) __bf16 Bl[2][64][72];
  float* shf = (float*)(&Al[0][0][0]);

  const int lane = t & 63, wv = t >> 6;
  const int wm = (wv & 1) * 32, wn = (wv >> 1) * 32;
  const int fr = lane & 15;
  const int rbase = (lane >> 4) * 4;

  unsigned* bar = (unsigned*)(ws + OFF_BAR);
  const __bf16* bsfB = (const __bf16*)(ws + OFF_BSFB);
  const __bf16* bsfT = (const __bf16*)(ws + OFF_BSFT);
  __bf16* SBh  = (__bf16*)(ws + OFF_SBH);
  __bf16* SBl  = (__bf16*)(ws + OFF_SBL);
  __bf16* T0B  = (__bf16*)(ws + OFF_T0);
  __bf16* MthB = (__bf16*)(ws + OFF_MTH);
  const __bf16* owB = (const __bf16*)(ws + OFF_OWB);
  const __bf16* gwT = (const __bf16*)(ws + OFF_GWT);
  const __bf16* phT = (const __bf16*)(ws + OFF_PHT);
  const __bf16* thT = (const __bf16*)(ws + OFF_THT);
  __bf16* UB  = (__bf16*)(ws + OFF_UB);
  __bf16* VB  = (__bf16*)(ws + OFF_VB);
  __bf16* VTB = (__bf16*)(ws + OFF_VTB);
  float* Z  = (float*)(ws + OFF_Z);
  float* Rr = (float*)(ws + OFF_R);
  const float* rpart = (const float*)(ws + OFF_RPART);
  const float* uv  = (const float*)(ws + OFF_UV);
  const float* v2f = (const float*)(ws + OFF_V2);
  const float* w2f = (const float*)(ws + OFF_W2);
  const float* s2f = (const float*)(ws + OFF_S2);
  float* rv2  = (float*)(ws + OFF_RV2);
  float* cvec = (float*)(ws + OFF_CVEC);
  float* gvec = (float*)(ws + OFF_GVEC);
  float* qv   = (float*)(ws + OFF_QV);
  float* PGN  = (float*)(ws + OFF_PGN);
  float* STATS = (float*)(ws + OFF_STATS);

  // ---------------- P0 ----------------
  if (blk < 64) {
    const int b = blk >> 4, tl = blk & 15;
    const int m0 = (tl >> 2) * 64, n0 = (tl & 3) * 64;
    f32x4 acc[2][2];
#pragma unroll
    for (int i = 0; i < 2; ++i)
#pragma unroll
      for (int j = 0; j < 2; ++j) acc[i][j] = (f32x4){0.f, 0.f, 0.f, 0.f};
    gemm_acc(bsfB + (size_t)b * 262144, bsfB + (size_t)b * 262144, 1024, m0, n0, Al, Bl, acc);
    __bf16* oh = SBh + (size_t)b * 65536;
    __bf16* ol = SBl + (size_t)b * 65536;
#pragma unroll
    for (int i = 0; i < 2; ++i)
#pragma unroll
      for (int r = 0; r < 4; ++r) {
        int m = m0 + wm + i * 16 + rbase + r;
#pragma unroll
        for (int j = 0; j < 2; ++j) {
          int n = n0 + wn + j * 16 + fr;
          float v = acc[i][j][r];
          __bf16 h = (__bf16)v;
          oh[(size_t)m * 256 + n] = h;
          ol[(size_t)m * 256 + n] = (__bf16)(v - (float)h);
        }
      }
  } else if (blk < 80) {
    const int tl = blk - 64;
    const int m0 = (tl >> 2) * 64, n0 = (tl & 3) * 64;
    f32x4 acc[2][2];
#pragma unroll
    for (int i = 0; i < 2; ++i)
#pragma unroll
      for (int j = 0; j < 2; ++j) acc[i][j] = (f32x4){0.f, 0.f, 0.f, 0.f};
    gemm_acc(owB, gwT, 256, m0, n0, Al, Bl, acc);
    store_bf16(UB, 256, acc, m0, n0, wm, wn, rbase, fr);
  } else if (blk < 96) {
    const int tl = blk - 80;
    const int m0 = (tl >> 2) * 64, n0 = (tl & 3) * 64;
    f32x4 acc[2][2];
#pragma unroll
    for (int i = 0; i < 2; ++i)
#pragma unroll
      for (int j = 0; j < 2; ++j) acc[i][j] = (f32x4){0.f, 0.f, 0.f, 0.f};
    gemm_acc(phT, thT, 256, m0, n0, Al, Bl, acc);
#pragma unroll
    for (int i = 0; i < 2; ++i)
#pragma unroll
      for (int r = 0; r < 4; ++r) {
        int m = m0 + wm + i * 16 + rbase + r;
#pragma unroll
        for (int j = 0; j < 2; ++j) {
          int n = n0 + wn + j * 16 + fr;
          __bf16 v = (__bf16)acc[i][j][r];
          VB[(size_t)m * 256 + n] = v;
          VTB[(size_t)n * 256 + m] = v;
        }
      }
  } else if (blk == 96) {
#pragma unroll
    for (int j2 = 0; j2 < 4; ++j2) {
      int idx = t + j2 * 256;
      float s = 0.f;
#pragma unroll
      for (int k = 0; k < 16; ++k) s += rpart[k * 1024 + idx];
      Rr[idx] = s;
    }
  }
  gsync(bar + 0, 256);

  // ---------------- P1 ----------------
  if (blk < 64) {
    const int b = blk >> 4, tl = blk & 15;
    const int m0 = (tl >> 2) * 64, n0 = (tl & 3) * 64;
    f32x4 acc[2][2];
#pragma unroll
    for (int i = 0; i < 2; ++i)
#pragma unroll
      for (int j = 0; j < 2; ++j) acc[i][j] = (f32x4){0.f, 0.f, 0.f, 0.f};
    gemm_acc(UB, SBh + (size_t)b * 65536, 256, m0, n0, Al, Bl, acc);
    gemm_acc(UB, SBl + (size_t)b * 65536, 256, m0, n0, Al, Bl, acc);
    store_bf16(T0B + (size_t)b * 65536, 256, acc, m0, n0, wm, wn, rbase, fr);
  } else if (blk < 80) {
    const int q = blk - 64;
    const int b = q >> 2, r0 = (q & 3) * 64;
    shf[t] = Rr[b * 256 + t];
    __syncthreads();
    for (int rr = 0; rr < 16; ++rr) {
      int row = r0 + wv * 16 + rr;
      const __bf16* p = UB + (size_t)row * 256;
      float pa = (float)p[lane] * shf[lane] + (float)p[64 + lane] * shf[64 + lane]
               + (float)p[128 + lane] * shf[128 + lane] + (float)p[192 + lane] * shf[192 + lane];
#pragma unroll
      for (int off = 32; off; off >>= 1) pa += __shfl_down(pa, off);
      if (lane == 0) cvec[b * 256 + row] = pa;
    }
  } else if (blk < 84) {
    const int b = blk - 80;
    shf[t] = Rr[b * 256 + t];
    __syncthreads();
    float acc2 = 0.f;
#pragma unroll 8
    for (int c2 = 0; c2 < 256; ++c2) acc2 += (float)VB[(size_t)c2 * 256 + t] * shf[c2];
    gvec[b * 256 + t] = acc2 * (1.f / 1024.f) + w2f[t];
  } else if (blk == 84) {
    float pa = Rr[wv * 256 + lane] * v2f[lane]
             + Rr[wv * 256 + 64 + lane] * v2f[64 + lane]
             + Rr[wv * 256 + 128 + lane] * v2f[128 + lane]
             + Rr[wv * 256 + 192 + lane] * v2f[192 + lane];
#pragma unroll
    for (int off = 32; off; off >>= 1) pa += __shfl_down(pa, off);
    if (lane == 0) rv2[wv] = pa;
  }
  gsync(bar + 1, 256);

  // ---------------- P2 ----------------
  if (blk < 64) {
    const int b = blk >> 4, tl = blk & 15;
    const int m0 = (tl >> 2) * 64, n0 = (tl & 3) * 64;
    f32x4 acc[2][2];
#pragma unroll
    for (int i = 0; i < 2; ++i)
#pragma unroll
      for (int j = 0; j < 2; ++j) acc[i][j] = (f32x4){0.f, 0.f, 0.f, 0.f};
    gemm_acc(T0B + (size_t)b * 65536, VTB, 256, m0, n0, Al, Bl, acc);
    const float s1024 = 1.f / 1024.f;
    __bf16* od = MthB + (size_t)b * 65536;
#pragma unroll
    for (int i = 0; i < 2; ++i)
#pragma unroll
      for (int r = 0; r < 4; ++r) {
        int m = m0 + wm + i * 16 + rbase + r;
        float um = uv[m], cv = cvec[b * 256 + m];
#pragma unroll
        for (int j = 0; j < 2; ++j) {
          int n = n0 + wn + j * 16 + fr;
          float val = acc[i][j][r] * s1024 + um * gvec[b * 256 + n] + cv * w2f[n] * s1024;
          od[(size_t)m * 256 + n] = (__bf16)val;
        }
      }
  } else if (blk < 68) {
    const int b = blk - 64;
    shf[t] = v2f[t];
    __syncthreads();
    const float rvb = rv2[b], s2v = s2f[0];
    for (int rr = 0; rr < 64; ++rr) {
      int row = wv * 64 + rr;
      const __bf16* p = T0B + (size_t)b * 65536 + (size_t)row * 256;
      float pa = (float)p[lane] * shf[lane] + (float)p[64 + lane] * shf[64 + lane]
               + (float)p[128 + lane] * shf[128 + lane] + (float)p[192 + lane] * shf[192 + lane];
#pragma unroll
      for (int off = 32; off; off >>= 1) pa += __shfl_down(pa, off);
      if (lane == 0)
        qv[b * 256 + row] = pa * (1.f / 1024.f)
                          + uv[row] * (rvb * (1.f / 1024.f) + s2v)
                          + cvec[b * 256 + row] * s2v * (1.f / 1024.f)
                          + ow_b[row];
    }
  }
  gsync(bar + 2, 256);

  // ---------------- P3: z = Mth*bsf + qv, with GN partial stats -------------
  {
    const int b = blk >> 6, t6 = blk & 63;
    const int mt = t6 >> 4, nt = t6 & 15;
    const int m0 = mt * 64, n0 = nt * 64;
    f32x4 acc[2][2];
#pragma unroll
    for (int i = 0; i < 2; ++i)
#pragma unroll
      for (int j = 0; j < 2; ++j) acc[i][j] = (f32x4){0.f, 0.f, 0.f, 0.f};
    gemm_acc(MthB + (size_t)b * 65536, bsfT + (size_t)b * 262144, 256, m0, n0, Al, Bl, acc);

    float gs[2] = {0.f, 0.f}, gq[2] = {0.f, 0.f};
    int gidx[2];
    float* zb = Z + (size_t)b * 262144;
#pragma unroll
    for (int i = 0; i < 2; ++i) {
      gidx[i] = (wm + i * 16 + rbase) >> 3;
#pragma unroll
      for (int r = 0; r < 4; ++r) {
        int m = m0 + wm + i * 16 + rbase + r;
        float qm = qv[b * 256 + m];
#pragma unroll
        for (int j = 0; j < 2; ++j) {
          int n = n0 + wn + j * 16 + fr;
          float v = acc[i][j][r] + qm;
          zb[(size_t)m * 1024 + n] = v;
          gs[i] += v;
          gq[i] += v * v;
        }
      }
    }
    __syncthreads();
    if (t < 16) shf[t] = 0.f;
    __syncthreads();
#pragma unroll
    for (int i = 0; i < 2; ++i) {
      atomicAdd(&shf[gidx[i] * 2], gs[i]);
      atomicAdd(&shf[gidx[i] * 2 + 1], gq[i]);
    }
    __syncthreads();
    if (t < 16) PGN[(((b * 4 + mt) * 16) + nt) * 16 + t] = shf[t];
  }
  gsync(bar + 3, 256);

  // ---------------- P4: finalize GN stats -----------------------------------
  if (blk == 0 && t < 128) {
    int b = t >> 5, g = t & 31, mt = g >> 3, gi = g & 7;
    float s = 0.f, q = 0.f;
#pragma unroll
    for (int nt = 0; nt < 16; ++nt) {
      int base = (((b * 4 + mt) * 16) + nt) * 16 + gi * 2;
      s += PGN[base];
      q += PGN[base + 1];
    }
    float mean = s * (1.f / 8192.f);
    float var = q * (1.f / 8192.f) - mean * mean;
    STATS[(b * 32 + g) * 2] = mean;
    STATS[(b * 32 + g) * 2 + 1] = rsqrtf(var + 1e-5f);
  }
}

// ---------------- fused GN + residual scatter (float4) ----------------------
__device__ __forceinline__ float4 gmix(float4 bz, float4 zz, float a, float c)
{
  float4 r;
  r.x = bz.x + zz.x * a + c;
  r.y = bz.y + zz.y * a + c;
  r.z = bz.z + zz.z * a + c;
  r.w = bz.w + zz.w * a + c;
  return r;
}
__device__ __forceinline__ float max4(float4 v)
{ return fmaxf(fmaxf(v.x, v.y), fmaxf(v.z, v.w)); }

__global__ __launch_bounds__(256) void scat_k(
    const char* __restrict__ ws,
    const float* __restrict__ f0, const float* __restrict__ f1,
    const float* __restrict__ f2, const float* __restrict__ f3,
    const float* __restrict__ f4,
    const float* __restrict__ gamma, const float* __restrict__ beta,
    float* __restrict__ out)
{
  const float* Z = (const float*)(ws + OFF_Z);
  const float* BSF = (const float*)(ws + OFF_BSF);
  const float2* ST = (const float2*)(ws + OFF_STATS);
  const int i4 = blockIdx.x * 256 + threadIdx.x;

  if (i4 < 4194304) {                       // f0: 128x128, upsample x4
    const int l = i4 << 2;
    const int x = l & 127, yy = (l >> 7) & 127, nc = l >> 14;
    const int ch = nc & 255, b = nc >> 8;
    float2 mv = ST[b * 32 + (ch >> 3)];
    float a = mv.y * gamma[ch];
    float c0 = beta[ch] - mv.x * a;
    size_t base = (size_t)nc * 1024 + ((yy >> 2) << 5) + (x >> 2);
    float v = BSF[base] + Z[base] * a + c0;
    float4 f = ((const float4*)f0)[i4];
    float4 o; o.x = f.x + v; o.y = f.y + v; o.z = f.z + v; o.w = f.w + v;
    ((float4*)out)[i4] = o;
  } else if (i4 < 5242880) {                // f1: 64x64, upsample x2
    const int l4 = i4 - 4194304;
    const int l = l4 << 2;
    const int x = l & 63, yy = (l >> 6) & 63, nc = l >> 12;
    const int ch = nc & 255, b = nc >> 8;
    float2 mv = ST[b * 32 + (ch >> 3)];
    float a = mv.y * gamma[ch];
    float c0 = beta[ch] - mv.x * a;
    size_t base = (size_t)nc * 1024 + ((yy >> 1) << 5) + (x >> 1);
    float v0 = BSF[base] + Z[base] * a + c0;
    float v1 = BSF[base + 1] + Z[base + 1] * a + c0;
    float4 f = ((const float4*)f1)[l4];
    float4 o; o.x = f.x + v0; o.y = f.y + v0; o.z = f.z + v1; o.w = f.w + v1;
    ((float4*)out)[i4] = o;
  } else if (i4 < 5505024) {                // f2: 32x32, identity
    const int l4 = i4 - 5242880;
    const int l = l4 << 2;
    const int nc = l >> 10, e = l & 1023;
    const int ch = nc & 255, b = nc >> 8;
    float2 mv = ST[b * 32 + (ch >> 3)];
    float a = mv.y * gamma[ch];
    float c0 = beta[ch] - mv.x * a;
    size_t base = (size_t)nc * 1024 + e;
    float4 z4 = *(const float4*)&Z[base];
    float4 b4 = *(const float4*)&BSF[base];
    float4 v = gmix(b4, z4, a, c0);
    float4 f = ((const float4*)f2)[l4];
    float4 o; o.x = f.x + v.x; o.y = f.y + v.y; o.z = f.z + v.z; o.w = f.w + v.w;
    ((float4*)out)[i4] = o;
  } else if (i4 < 5570560) {                // f3: 16x16, maxpool 2x2
    const int l4 = i4 - 5505024;
    const int l = l4 << 2;
    const int x = l & 15, yy = (l >> 4) & 15, nc = l >> 8;
    const int ch = nc & 255, b = nc >> 8;
    float2 mv = ST[b * 32 + (ch >> 3)];
    float a = mv.y * gamma[ch];
    float c0 = beta[ch] - mv.x * a;
    size_t base = (size_t)nc * 1024;
    const int p0 = (yy * 2) * 32 + (x * 2);
    float4 r0a = gmix(*(const float4*)&BSF[base + p0],      *(const float4*)&Z[base + p0],      a, c0);
    float4 r0b = gmix(*(const float4*)&BSF[base + p0 + 4],  *(const float4*)&Z[base + p0 + 4],  a, c0);
    float4 r1a = gmix(*(const float4*)&BSF[base + p0 + 32], *(const float4*)&Z[base + p0 + 32], a, c0);
    float4 r1b = gmix(*(const float4*)&BSF[base + p0 + 36], *(const float4*)&Z[base + p0 + 36], a, c0);
    float4 f = ((const float4*)f3)[l4];
    float4 o;
    o.x = f.x + fmaxf(fmaxf(r0a.x, r0a.y), fmaxf(r1a.x, r1a.y));
    o.y = f.y + fmaxf(fmaxf(r0a.z, r0a.w), fmaxf(r1a.z, r1a.w));
    o.z = f.z + fmaxf(fmaxf(r0b.x, r0b.y), fmaxf(r1b.x, r1b.y));
    o.w = f.w + fmaxf(fmaxf(r0b.z, r0b.w), fmaxf(r1b.z, r1b.w));
    ((float4*)out)[i4] = o;
  } else {                                   // f4: 8x8, maxpool 4x4
    const int l4 = i4 - 5570560;
    const int l = l4 << 2;
    const int x = l & 7, yy = (l >> 3) & 7, nc = l >> 6;
    const int ch = nc & 255, b = nc >> 8;
    float2 mv = ST[b * 32 + (ch >> 3)];
    float a = mv.y * gamma[ch];
    float c0 = beta[ch] - mv.x * a;
    size_t base = (size_t)nc * 1024;
    float4 mx = {-3.4e38f, -3.4e38f, -3.4e38f, -3.4e38f};
#pragma unroll
    for (int r = 0; r < 4; ++r) {
      const float* zp = &Z[base + (size_t)(yy * 4 + r) * 32 + x * 4];
      const float* bp = &BSF[base + (size_t)(yy * 4 + r) * 32 + x * 4];
      float4 q0 = gmix(*(const float4*)(bp),      *(const float4*)(zp),      a, c0);
      float4 q1 = gmix(*(const float4*)(bp + 4),  *(const float4*)(zp + 4),  a, c0);
      float4 q2 = gmix(*(const float4*)(bp + 8),  *(const float4*)(zp + 8),  a, c0);
      float4 q3 = gmix(*(const float4*)(bp + 12), *(const float4*)(zp + 12), a, c0);
      mx.x = fmaxf(mx.x, max4(q0));
      mx.y = fmaxf(mx.y, max4(q1));
      mx.z = fmaxf(mx.z, max4(q2));
      mx.w = fmaxf(mx.w, max4(q3));
    }
    float4 f = ((const float4*)f4)[l4];
    float4 o; o.x = f.x + mx.x; o.y = f.y + mx.y; o.z = f.z + mx.z; o.w = f.w + mx.w;
    ((float4*)out)[i4] = o;
  }
}

// ---------------------------------------------------------------------------
extern "C" void kernel_launch(void* const* d_in, const int* in_sizes, int n_in,
                              void* d_out, int out_size, void* d_ws, size_t ws_size,
                              hipStream_t stream)
{
  (void)in_sizes; (void)n_in; (void)out_size; (void)ws_size;
  const float* f0   = (const float*)d_in[0];
  const float* f1   = (const float*)d_in[1];
  const float* f2   = (const float*)d_in[2];
  const float* f3   = (const float*)d_in[3];
  const float* f4   = (const float*)d_in[4];
  const float* g_w  = (const float*)d_in[5];
  const float* g_b  = (const float*)d_in[6];
  const float* th_w = (const float*)d_in[7];
  const float* th_b = (const float*)d_in[8];
  const float* ph_w = (const float*)d_in[9];
  const float* ph_b = (const float*)d_in[10];
  const float* ow_w = (const float*)d_in[11];
  const float* ow_b = (const float*)d_in[12];
  const float* gn_g = (const float*)d_in[13];
  const float* gn_b = (const float*)d_in[14];
  char* ws = (char*)d_ws;

  // 1) gather + weight prep (independent roles, one launch)
  prep_k<<<311, 256, 0, stream>>>(f0, f1, f2, f3, f4,
                                  g_w, ph_w, th_w, ow_w,
                                  g_b, ph_b, th_b, ws);
  // 2) persistent middle: S -> T0 -> Mth -> z(+GN stats) with grid barriers
  middle_k<<<256, 256, 0, stream>>>(ws, ow_b);
  // 3) fused GN-normalize + residual scatter
  scat_k<<<21824, 256, 0, stream>>>(ws, f0, f1, f2, f3, f4, gn_g, gn_b,
                                    (float*)d_out);
}

// Round 2
// 313.180 us; speedup vs baseline: 1.0947x; 1.0947x over previous
//
#include <hip/hip_runtime.h>

typedef __bf16 bf16x8 __attribute__((ext_vector_type(8)));
typedef float f32x4 __attribute__((ext_vector_type(4)));

// ---------------------------------------------------------------------------
// Workspace layout (bytes):
#define OFF_BSF   0x000000   // f32  [4][256][1024]  4 MB
#define OFF_BSFT  0x400000   // bf16 [4][1024][256]  2 MB   (spatial-major)
#define OFF_BSFB  0x600000   // bf16 [4][256][1024]  2 MB   (channel-major)
#define OFF_Z     0x800000   // f32  [4][256][1024]  4 MB
#define OFF_SBH   0xC00000   // bf16 [4][256][256]   512 KB  S hi
#define OFF_SBL   0xC80000   // bf16 [4][256][256]   512 KB  S lo (residual)
#define OFF_T0    0xD00000   // bf16 [4][256][256]   T0 = U*S
#define OFF_MTH   0xD80000   // bf16 [4][256][256]   Mth
#define OFF_OWB   0xE00000   // bf16 [256][256]
#define OFF_GWT   0xE20000   // bf16 g_w^T
#define OFF_PHT   0xE40000   // bf16 ph_w^T
#define OFF_THT   0xE60000   // bf16 th_w^T
#define OFF_UB    0xE80000   // bf16 U = ow*g_w
#define OFF_VB    0xEA0000   // bf16 V = ph_w^T*th_w
#define OFF_VTB   0xEC0000   // bf16 V^T
#define OFF_RPART 0xEE0000   // f32 [16][1024] row-sum partials
#define OFF_R     0xEF0000   // f32 [4][256]  r = bsf.1
#define OFF_UV    0xEF1000   // f32 [256]  u = ow*g_b
#define OFF_V2    0xEF1400   // f32 [256]  v2 = ph_w^T*th_b
#define OFF_W2    0xEF1800   // f32 [256]  w2 = th_w^T*ph_b
#define OFF_S2    0xEF1C00   // f32 s2 = ph_b.th_b
#define OFF_RV2   0xEF1C40   // f32 [4]  r.v2
#define OFF_CVEC  0xEF2000   // f32 [4][256]  U*r
#define OFF_GVEC  0xEF3000   // f32 [4][256]  (V^T r)/N + w2
#define OFF_QV    0xEF4000   // f32 [4][256]  per-channel constant of z
#define OFF_PGN   0xEF5000   // f32 [4][4][16][8][2] GN partials  16 KB
#define OFF_STATS 0xEF9000   // f32 [4][32][2] (mean, inv)
#define OFF_BAR   0xEF9400   // u32 [8] grid-barrier counters
// ---------------------------------------------------------------------------

// ---------------- prep: gather + weight cvt/transpose + bias matvecs --------
__global__ __launch_bounds__(256) void prep_k(
    const float* __restrict__ f0, const float* __restrict__ f1,
    const float* __restrict__ f2, const float* __restrict__ f3,
    const float* __restrict__ f4,
    const float* __restrict__ g_w, const float* __restrict__ ph_w,
    const float* __restrict__ th_w, const float* __restrict__ ow_w,
    const float* __restrict__ g_b, const float* __restrict__ ph_b,
    const float* __restrict__ th_b,
    char* __restrict__ ws)
{
  const int blk = blockIdx.x, t = threadIdx.x;
  __shared__ __attribute__((aligned(16))) union {
    __bf16 Lt[64][66];
    __bf16 T[64][72];
    float vec[256];
  } sm;

  if (blk < 256) {
    // ---- gather: bsf fp32 + bsfB bf16 (ch-major) + bsfT bf16 (sp-major) + rowsum partials
    float*  bsf   = (float*)(ws + OFF_BSF);
    __bf16* bsfT  = (__bf16*)(ws + OFF_BSFT);
    __bf16* bsfB  = (__bf16*)(ws + OFF_BSFB);
    float*  rpart = (float*)(ws + OFF_RPART);
    const int sblk = blk & 15, cblk = (blk >> 4) & 3, b = blk >> 6;
    const int c0 = cblk * 64, s0 = sblk * 64;
    const int spl = t & 63, sp = s0 + spl;
    const int y = sp >> 5, x = sp & 31;
#pragma unroll
    for (int i = 0; i < 16; ++i) {
      const int cl = (t >> 6) + i * 4;
      const int nc = b * 256 + c0 + cl;

      const float* p0 = f0 + (size_t)nc * 16384 + (y * 4) * 128 + x * 4;
      float4 r0 = *(const float4*)(p0);
      float4 r1 = *(const float4*)(p0 + 128);
      float4 r2 = *(const float4*)(p0 + 256);
      float4 r3 = *(const float4*)(p0 + 384);
      float a  = fmaxf(fmaxf(r0.x, r0.y), fmaxf(r0.z, r0.w));
      float bb = fmaxf(fmaxf(r1.x, r1.y), fmaxf(r1.z, r1.w));
      float c  = fmaxf(fmaxf(r2.x, r2.y), fmaxf(r2.z, r2.w));
      float d  = fmaxf(fmaxf(r3.x, r3.y), fmaxf(r3.z, r3.w));
      float m0v = fmaxf(fmaxf(a, bb), fmaxf(c, d));

      const float* p1 = f1 + (size_t)nc * 4096 + (y * 2) * 64 + x * 2;
      float2 s0v = *(const float2*)(p1);
      float2 s1v = *(const float2*)(p1 + 64);
      float m1v = fmaxf(fmaxf(s0v.x, s0v.y), fmaxf(s1v.x, s1v.y));

      float v2 = f2[(size_t)nc * 1024 + sp];
      float v3 = f3[(size_t)nc * 256 + (y >> 1) * 16 + (x >> 1)];
      float v4 = f4[(size_t)nc * 64  + (y >> 2) * 8  + (x >> 2)];
      float val = (m0v + m1v + v2 + v3 + v4) * 0.2f;
      bsf[(size_t)nc * 1024 + sp]  = val;
      bsfB[(size_t)nc * 1024 + sp] = (__bf16)val;
      sm.Lt[cl][spl] = (__bf16)val;
      float rs = val;
#pragma unroll
      for (int off = 32; off; off >>= 1) rs += __shfl_down(rs, off);
      if (spl == 0) rpart[sblk * 1024 + nc] = rs;
    }
    __syncthreads();
#pragma unroll
    for (int i = 0; i < 16; ++i) {
      int linear = t + i * 256;
      int spl2 = linear >> 6, cl2 = linear & 63;
      bsfT[((size_t)b * 1024 + s0 + spl2) * 256 + c0 + cl2] = sm.Lt[cl2][spl2];
    }
  } else if (blk < 304) {
    // ---- weight transposes (fp32 -> bf16): gwT/phT/thT, 64x64 tiles
    const int w = (blk - 256) >> 4, tl = (blk - 256) & 15;
    const float* src = (w == 0) ? g_w : (w == 1) ? ph_w : th_w;
    __bf16* dst = (__bf16*)(ws + ((w == 0) ? OFF_GWT : (w == 1) ? OFF_PHT : OFF_THT));
    const int ti = (tl >> 2) * 64, tj = (tl & 3) * 64;
#pragma unroll
    for (int i = 0; i < 4; ++i) {
      int idx = i * 256 + t;
      int r = idx >> 4, c4 = (idx & 15) << 2;
      float4 v = *(const float4*)&src[(size_t)(ti + r) * 256 + tj + c4];
      sm.T[c4 + 0][r] = (__bf16)v.x;
      sm.T[c4 + 1][r] = (__bf16)v.y;
      sm.T[c4 + 2][r] = (__bf16)v.z;
      sm.T[c4 + 3][r] = (__bf16)v.w;
    }
    __syncthreads();
#pragma unroll
    for (int i = 0; i < 2; ++i) {
      int idx = i * 256 + t;
      int aa = idx >> 3, cc = (idx & 7) << 3;
      bf16x8 o = *(const bf16x8*)&sm.T[aa][cc];
      *(bf16x8*)&dst[(size_t)(tj + aa) * 256 + ti + cc] = o;
    }
  } else if (blk < 308) {
    // ---- owB plain convert
    const int r0 = (blk - 304) * 64;
    __bf16* owB = (__bf16*)(ws + OFF_OWB);
#pragma unroll
    for (int i = 0; i < 8; ++i) {
      int lin = i * 2048 + t * 8;
      size_t gidx = (size_t)r0 * 256 + lin;
      float4 v0 = *(const float4*)&ow_w[gidx];
      float4 v1 = *(const float4*)&ow_w[gidx + 4];
      bf16x8 o;
      o[0] = (__bf16)v0.x; o[1] = (__bf16)v0.y; o[2] = (__bf16)v0.z; o[3] = (__bf16)v0.w;
      o[4] = (__bf16)v1.x; o[5] = (__bf16)v1.y; o[6] = (__bf16)v1.z; o[7] = (__bf16)v1.w;
      *(bf16x8*)&owB[gidx] = o;
    }
  } else if (blk == 308) {
    // ---- u = ow_w . g_b  (wave-per-row dots) ; zero grid-barrier counters
    float* uv = (float*)(ws + OFF_UV);
    unsigned* bar = (unsigned*)(ws + OFF_BAR);
    sm.vec[t] = g_b[t];
    __syncthreads();
    const int wv = t >> 6, l = t & 63;
    for (int rr = 0; rr < 64; ++rr) {
      int row = wv * 64 + rr;
      const float* p = ow_w + (size_t)row * 256;
      float pa = p[l] * sm.vec[l] + p[64 + l] * sm.vec[64 + l]
               + p[128 + l] * sm.vec[128 + l] + p[192 + l] * sm.vec[192 + l];
#pragma unroll
      for (int off = 32; off; off >>= 1) pa += __shfl_down(pa, off);
      if (l == 0) uv[row] = pa;
    }
    if (t < 8) bar[t] = 0u;
  } else if (blk == 309) {
    // ---- v2 = ph_w^T . th_b (column dot, coalesced) ; s2 = ph_b.th_b
    float* v2 = (float*)(ws + OFF_V2);
    float* s2 = (float*)(ws + OFF_S2);
    float acc = 0.f;
#pragma unroll 8
    for (int c = 0; c < 256; ++c) acc += ph_w[(size_t)c * 256 + t] * th_b[c];
    v2[t] = acc;
    if (t < 64) {
      float pa = ph_b[t] * th_b[t] + ph_b[64 + t] * th_b[64 + t]
               + ph_b[128 + t] * th_b[128 + t] + ph_b[192 + t] * th_b[192 + t];
#pragma unroll
      for (int off = 32; off; off >>= 1) pa += __shfl_down(pa, off);
      if (t == 0) s2[0] = pa;
    }
  } else {
    // ---- w2 = th_w^T . ph_b
    float* w2 = (float*)(ws + OFF_W2);
    float acc = 0.f;
#pragma unroll 8
    for (int c = 0; c < 256; ++c) acc += th_w[(size_t)c * 256 + t] * ph_b[c];
    w2[t] = acc;
  }
}

// ---------------- GEMM accumulate core (64x64 tile, 4 waves, dbuf) ----------
__device__ __forceinline__ void gemm_acc(
    const __bf16* __restrict__ A, const __bf16* __restrict__ B,
    const int K, const int m0, const int n0,
    __bf16 (*Al)[64][72], __bf16 (*Bl)[64][72],
    f32x4 acc[2][2])
{
  const int t = threadIdx.x;
  const int lane = t & 63, wv = t >> 6;
  const int wm = (wv & 1) * 32, wn = (wv >> 1) * 32;
  const int fr = lane & 15, lk = (lane >> 4) * 8;
  const int sr = t >> 2, sk = (t & 3) * 16;

  const __bf16* Ar = A + (size_t)(m0 + sr) * K + sk;
  const __bf16* Br = B + (size_t)(n0 + sr) * K + sk;

  bf16x8 ra0 = *(const bf16x8*)(Ar);
  bf16x8 ra1 = *(const bf16x8*)(Ar + 8);
  bf16x8 rb0 = *(const bf16x8*)(Br);
  bf16x8 rb1 = *(const bf16x8*)(Br + 8);

  const int nIter = K >> 6;
  int p = 0;
  for (int it = 0; it < nIter; ++it) {
    *(bf16x8*)&Al[p][sr][sk]     = ra0;
    *(bf16x8*)&Al[p][sr][sk + 8] = ra1;
    *(bf16x8*)&Bl[p][sr][sk]     = rb0;
    *(bf16x8*)&Bl[p][sr][sk + 8] = rb1;
    __syncthreads();
    if (it + 1 < nIter) {
      const __bf16* An = Ar + (size_t)(it + 1) * 64;
      const __bf16* Bn = Br + (size_t)(it + 1) * 64;
      ra0 = *(const bf16x8*)(An);
      ra1 = *(const bf16x8*)(An + 8);
      rb0 = *(const bf16x8*)(Bn);
      rb1 = *(const bf16x8*)(Bn + 8);
    }
#pragma unroll
    for (int kk = 0; kk < 64; kk += 32) {
      bf16x8 a0 = *(const bf16x8*)&Al[p][wm + fr][kk + lk];
      bf16x8 a1 = *(const bf16x8*)&Al[p][wm + 16 + fr][kk + lk];
      bf16x8 b0 = *(const bf16x8*)&Bl[p][wn + fr][kk + lk];
      bf16x8 b1 = *(const bf16x8*)&Bl[p][wn + 16 + fr][kk + lk];
      acc[0][0] = __builtin_amdgcn_mfma_f32_16x16x32_bf16(a0, b0, acc[0][0], 0, 0, 0);
      acc[0][1] = __builtin_amdgcn_mfma_f32_16x16x32_bf16(a0, b1, acc[0][1], 0, 0, 0);
      acc[1][0] = __builtin_amdgcn_mfma_f32_16x16x32_bf16(a1, b0, acc[1][0], 0, 0, 0);
      acc[1][1] = __builtin_amdgcn_mfma_f32_16x16x32_bf16(a1, b1, acc[1][1], 0, 0, 0);
    }
    __syncthreads();
    p ^= 1;
  }
}

__device__ __forceinline__ void store_bf16(
    __bf16* dst, int ldst, const f32x4 acc[2][2],
    int m0, int n0, int wm, int wn, int rbase, int fr)
{
#pragma unroll
  for (int i = 0; i < 2; ++i)
#pragma unroll
    for (int r = 0; r < 4; ++r) {
      int m = m0 + wm + i * 16 + rbase + r;
#pragma unroll
      for (int j = 0; j < 2; ++j) {
        int n = n0 + wn + j * 16 + fr;
        dst[(size_t)m * ldst + n] = (__bf16)acc[i][j][r];
      }
    }
}

// ---------------- software grid barrier (single-poller per block) -----------
// Round-0 failure: all 65536 threads spun on one cacheline with agent-scope
// loads -> coherence-point congestion starved the releasing atomicAdds
// (275 us @ 0.4% VALUBusy). Fix: only thread 0 of each block polls (256
// pollers), s_sleep backoff; other waves park at s_barrier.
__device__ __forceinline__ void gsync(unsigned* c, unsigned nb)
{
  __syncthreads();
  __threadfence();                 // release: this block's writes -> visible
  if (threadIdx.x == 0) {
    atomicAdd(c, 1u);
    while (__hip_atomic_load(c, __ATOMIC_RELAXED, __HIP_MEMORY_SCOPE_AGENT) < nb)
      __builtin_amdgcn_s_sleep(8);
  }
  __syncthreads();
  __threadfence();                 // acquire: invalidate before fresh reads
}

// ---------------- persistent middle kernel ----------------------------------
// P0: S = bsf.bsf^T (hi/lo bf16) ; U = ow*g_w ; V = ph_w^T*th_w ; r finalize
// P1: T0 = U*S (split-compensated) ; cvec = U*r ; gvec = (V^T r)/N + w2 ; rv2
// P2: Mth = T0*V/N + rank-1 bias terms ; qv = per-channel const of z
// P3: z = Mth*bsf + qv  (+ GN partial stats)
// P4: GN stats finalize
__global__ __launch_bounds__(256) void middle_k(char* __restrict__ ws,
                                                const float* __restrict__ ow_b)
{
  const int blk = blockIdx.x, t = threadIdx.x;
  __shared__ __attribute__((aligned(16))) __bf16 Al[2][64][72];
  __shared__ __attribute__((aligned(16))) __bf16 Bl[2][64][72];
  float* shf = (float*)(&Al[0][0][0]);

  const int lane = t & 63, wv = t >> 6;
  const int wm = (wv & 1) * 32, wn = (wv >> 1) * 32;
  const int fr = lane & 15;
  const int rbase = (lane >> 4) * 4;

  unsigned* bar = (unsigned*)(ws + OFF_BAR);
  const __bf16* bsfB = (const __bf16*)(ws + OFF_BSFB);
  const __bf16* bsfT = (const __bf16*)(ws + OFF_BSFT);
  __bf16* SBh  = (__bf16*)(ws + OFF_SBH);
  __bf16* SBl  = (__bf16*)(ws + OFF_SBL);
  __bf16* T0B  = (__bf16*)(ws + OFF_T0);
  __bf16* MthB = (__bf16*)(ws + OFF_MTH);
  const __bf16* owB = (const __bf16*)(ws + OFF_OWB);
  const __bf16* gwT = (const __bf16*)(ws + OFF_GWT);
  const __bf16* phT = (const __bf16*)(ws + OFF_PHT);
  const __bf16* thT = (const __bf16*)(ws + OFF_THT);
  __bf16* UB  = (__bf16*)(ws + OFF_UB);
  __bf16* VB  = (__bf16*)(ws + OFF_VB);
  __bf16* VTB = (__bf16*)(ws + OFF_VTB);
  float* Z  = (float*)(ws + OFF_Z);
  float* Rr = (float*)(ws + OFF_R);
  const float* rpart = (const float*)(ws + OFF_RPART);
  const float* uv  = (const float*)(ws + OFF_UV);
  const float* v2f = (const float*)(ws + OFF_V2);
  const float* w2f = (const float*)(ws + OFF_W2);
  const float* s2f = (const float*)(ws + OFF_S2);
  float* rv2  = (float*)(ws + OFF_RV2);
  float* cvec = (float*)(ws + OFF_CVEC);
  float* gvec = (float*)(ws + OFF_GVEC);
  float* qv   = (float*)(ws + OFF_QV);
  float* PGN  = (float*)(ws + OFF_PGN);
  float* STATS = (float*)(ws + OFF_STATS);

  // ---------------- P0 ----------------
  if (blk < 64) {
    const int b = blk >> 4, tl = blk & 15;
    const int m0 = (tl >> 2) * 64, n0 = (tl & 3) * 64;
    f32x4 acc[2][2];
#pragma unroll
    for (int i = 0; i < 2; ++i)
#pragma unroll
      for (int j = 0; j < 2; ++j) acc[i][j] = (f32x4){0.f, 0.f, 0.f, 0.f};
    gemm_acc(bsfB + (size_t)b * 262144, bsfB + (size_t)b * 262144, 1024, m0, n0, Al, Bl, acc);
    __bf16* oh = SBh + (size_t)b * 65536;
    __bf16* ol = SBl + (size_t)b * 65536;
#pragma unroll
    for (int i = 0; i < 2; ++i)
#pragma unroll
      for (int r = 0; r < 4; ++r) {
        int m = m0 + wm + i * 16 + rbase + r;
#pragma unroll
        for (int j = 0; j < 2; ++j) {
          int n = n0 + wn + j * 16 + fr;
          float v = acc[i][j][r];
          __bf16 h = (__bf16)v;
          oh[(size_t)m * 256 + n] = h;
          ol[(size_t)m * 256 + n] = (__bf16)(v - (float)h);
        }
      }
  } else if (blk < 80) {
    const int tl = blk - 64;
    const int m0 = (tl >> 2) * 64, n0 = (tl & 3) * 64;
    f32x4 acc[2][2];
#pragma unroll
    for (int i = 0; i < 2; ++i)
#pragma unroll
      for (int j = 0; j < 2; ++j) acc[i][j] = (f32x4){0.f, 0.f, 0.f, 0.f};
    gemm_acc(owB, gwT, 256, m0, n0, Al, Bl, acc);
    store_bf16(UB, 256, acc, m0, n0, wm, wn, rbase, fr);
  } else if (blk < 96) {
    const int tl = blk - 80;
    const int m0 = (tl >> 2) * 64, n0 = (tl & 3) * 64;
    f32x4 acc[2][2];
#pragma unroll
    for (int i = 0; i < 2; ++i)
#pragma unroll
      for (int j = 0; j < 2; ++j) acc[i][j] = (f32x4){0.f, 0.f, 0.f, 0.f};
    gemm_acc(phT, thT, 256, m0, n0, Al, Bl, acc);
#pragma unroll
    for (int i = 0; i < 2; ++i)
#pragma unroll
      for (int r = 0; r < 4; ++r) {
        int m = m0 + wm + i * 16 + rbase + r;
#pragma unroll
        for (int j = 0; j < 2; ++j) {
          int n = n0 + wn + j * 16 + fr;
          __bf16 v = (__bf16)acc[i][j][r];
          VB[(size_t)m * 256 + n] = v;
          VTB[(size_t)n * 256 + m] = v;
        }
      }
  } else if (blk == 96) {
#pragma unroll
    for (int j2 = 0; j2 < 4; ++j2) {
      int idx = t + j2 * 256;
      float s = 0.f;
#pragma unroll
      for (int k = 0; k < 16; ++k) s += rpart[k * 1024 + idx];
      Rr[idx] = s;
    }
  }
  gsync(bar + 0, 256);

  // ---------------- P1 ----------------
  if (blk < 64) {
    const int b = blk >> 4, tl = blk & 15;
    const int m0 = (tl >> 2) * 64, n0 = (tl & 3) * 64;
    f32x4 acc[2][2];
#pragma unroll
    for (int i = 0; i < 2; ++i)
#pragma unroll
      for (int j = 0; j < 2; ++j) acc[i][j] = (f32x4){0.f, 0.f, 0.f, 0.f};
    gemm_acc(UB, SBh + (size_t)b * 65536, 256, m0, n0, Al, Bl, acc);
    gemm_acc(UB, SBl + (size_t)b * 65536, 256, m0, n0, Al, Bl, acc);
    store_bf16(T0B + (size_t)b * 65536, 256, acc, m0, n0, wm, wn, rbase, fr);
  } else if (blk < 80) {
    const int q = blk - 64;
    const int b = q >> 2, r0 = (q & 3) * 64;
    shf[t] = Rr[b * 256 + t];
    __syncthreads();
    for (int rr = 0; rr < 16; ++rr) {
      int row = r0 + wv * 16 + rr;
      const __bf16* p = UB + (size_t)row * 256;
      float pa = (float)p[lane] * shf[lane] + (float)p[64 + lane] * shf[64 + lane]
               + (float)p[128 + lane] * shf[128 + lane] + (float)p[192 + lane] * shf[192 + lane];
#pragma unroll
      for (int off = 32; off; off >>= 1) pa += __shfl_down(pa, off);
      if (lane == 0) cvec[b * 256 + row] = pa;
    }
  } else if (blk < 84) {
    const int b = blk - 80;
    shf[t] = Rr[b * 256 + t];
    __syncthreads();
    float acc2 = 0.f;
#pragma unroll 8
    for (int c2 = 0; c2 < 256; ++c2) acc2 += (float)VB[(size_t)c2 * 256 + t] * shf[c2];
    gvec[b * 256 + t] = acc2 * (1.f / 1024.f) + w2f[t];
  } else if (blk == 84) {
    float pa = Rr[wv * 256 + lane] * v2f[lane]
             + Rr[wv * 256 + 64 + lane] * v2f[64 + lane]
             + Rr[wv * 256 + 128 + lane] * v2f[128 + lane]
             + Rr[wv * 256 + 192 + lane] * v2f[192 + lane];
#pragma unroll
    for (int off = 32; off; off >>= 1) pa += __shfl_down(pa, off);
    if (lane == 0) rv2[wv] = pa;
  }
  gsync(bar + 1, 256);

  // ---------------- P2 ----------------
  if (blk < 64) {
    const int b = blk >> 4, tl = blk & 15;
    const int m0 = (tl >> 2) * 64, n0 = (tl & 3) * 64;
    f32x4 acc[2][2];
#pragma unroll
    for (int i = 0; i < 2; ++i)
#pragma unroll
      for (int j = 0; j < 2; ++j) acc[i][j] = (f32x4){0.f, 0.f, 0.f, 0.f};
    gemm_acc(T0B + (size_t)b * 65536, VTB, 256, m0, n0, Al, Bl, acc);
    const float s1024 = 1.f / 1024.f;
    __bf16* od = MthB + (size_t)b * 65536;
#pragma unroll
    for (int i = 0; i < 2; ++i)
#pragma unroll
      for (int r = 0; r < 4; ++r) {
        int m = m0 + wm + i * 16 + rbase + r;
        float um = uv[m], cv = cvec[b * 256 + m];
#pragma unroll
        for (int j = 0; j < 2; ++j) {
          int n = n0 + wn + j * 16 + fr;
          float val = acc[i][j][r] * s1024 + um * gvec[b * 256 + n] + cv * w2f[n] * s1024;
          od[(size_t)m * 256 + n] = (__bf16)val;
        }
      }
  } else if (blk < 68) {
    const int b = blk - 64;
    shf[t] = v2f[t];
    __syncthreads();
    const float rvb = rv2[b], s2v = s2f[0];
    for (int rr = 0; rr < 64; ++rr) {
      int row = wv * 64 + rr;
      const __bf16* p = T0B + (size_t)b * 65536 + (size_t)row * 256;
      float pa = (float)p[lane] * shf[lane] + (float)p[64 + lane] * shf[64 + lane]
               + (float)p[128 + lane] * shf[128 + lane] + (float)p[192 + lane] * shf[192 + lane];
#pragma unroll
      for (int off = 32; off; off >>= 1) pa += __shfl_down(pa, off);
      if (lane == 0)
        qv[b * 256 + row] = pa * (1.f / 1024.f)
                          + uv[row] * (rvb * (1.f / 1024.f) + s2v)
                          + cvec[b * 256 + row] * s2v * (1.f / 1024.f)
                          + ow_b[row];
    }
  }
  gsync(bar + 2, 256);

  // ---------------- P3: z = Mth*bsf + qv, with GN partial stats -------------
  {
    const int b = blk >> 6, t6 = blk & 63;
    const int mt = t6 >> 4, nt = t6 & 15;
    const int m0 = mt * 64, n0 = nt * 64;
    f32x4 acc[2][2];
#pragma unroll
    for (int i = 0; i < 2; ++i)
#pragma unroll
      for (int j = 0; j < 2; ++j) acc[i][j] = (f32x4){0.f, 0.f, 0.f, 0.f};
    gemm_acc(MthB + (size_t)b * 65536, bsfT + (size_t)b * 262144, 256, m0, n0, Al, Bl, acc);

    float gs[2] = {0.f, 0.f}, gq[2] = {0.f, 0.f};
    int gidx[2];
    float* zb = Z + (size_t)b * 262144;
#pragma unroll
    for (int i = 0; i < 2; ++i) {
      gidx[i] = (wm + i * 16 + rbase) >> 3;
#pragma unroll
      for (int r = 0; r < 4; ++r) {
        int m = m0 + wm + i * 16 + rbase + r;
        float qm = qv[b * 256 + m];
#pragma unroll
        for (int j = 0; j < 2; ++j) {
          int n = n0 + wn + j * 16 + fr;
          float v = acc[i][j][r] + qm;
          zb[(size_t)m * 1024 + n] = v;
          gs[i] += v;
          gq[i] += v * v;
        }
      }
    }
    __syncthreads();
    if (t < 16) shf[t] = 0.f;
    __syncthreads();
#pragma unroll
    for (int i = 0; i < 2; ++i) {
      atomicAdd(&shf[gidx[i] * 2], gs[i]);
      atomicAdd(&shf[gidx[i] * 2 + 1], gq[i]);
    }
    __syncthreads();
    if (t < 16) PGN[(((b * 4 + mt) * 16) + nt) * 16 + t] = shf[t];
  }
  gsync(bar + 3, 256);

  // ---------------- P4: finalize GN stats -----------------------------------
  if (blk == 0 && t < 128) {
    int b = t >> 5, g = t & 31, mt = g >> 3, gi = g & 7;
    float s = 0.f, q = 0.f;
#pragma unroll
    for (int nt = 0; nt < 16; ++nt) {
      int base = (((b * 4 + mt) * 16) + nt) * 16 + gi * 2;
      s += PGN[base];
      q += PGN[base + 1];
    }
    float mean = s * (1.f / 8192.f);
    float var = q * (1.f / 8192.f) - mean * mean;
    STATS[(b * 32 + g) * 2] = mean;
    STATS[(b * 32 + g) * 2 + 1] = rsqrtf(var + 1e-5f);
  }
}

// ---------------- fused GN + residual scatter (float4) ----------------------
__device__ __forceinline__ float4 gmix(float4 bz, float4 zz, float a, float c)
{
  float4 r;
  r.x = bz.x + zz.x * a + c;
  r.y = bz.y + zz.y * a + c;
  r.z = bz.z + zz.z * a + c;
  r.w = bz.w + zz.w * a + c;
  return r;
}
__device__ __forceinline__ float max4(float4 v)
{ return fmaxf(fmaxf(v.x, v.y), fmaxf(v.z, v.w)); }

__global__ __launch_bounds__(256) void scat_k(
    const char* __restrict__ ws,
    const float* __restrict__ f0, const float* __restrict__ f1,
    const float* __restrict__ f2, const float* __restrict__ f3,
    const float* __restrict__ f4,
    const float* __restrict__ gamma, const float* __restrict__ beta,
    float* __restrict__ out)
{
  const float* Z = (const float*)(ws + OFF_Z);
  const float* BSF = (const float*)(ws + OFF_BSF);
  const float2* ST = (const float2*)(ws + OFF_STATS);
  const int i4 = blockIdx.x * 256 + threadIdx.x;

  if (i4 < 4194304) {                       // f0: 128x128, upsample x4
    const int l = i4 << 2;
    const int x = l & 127, yy = (l >> 7) & 127, nc = l >> 14;
    const int ch = nc & 255, b = nc >> 8;
    float2 mv = ST[b * 32 + (ch >> 3)];
    float a = mv.y * gamma[ch];
    float c0 = beta[ch] - mv.x * a;
    size_t base = (size_t)nc * 1024 + ((yy >> 2) << 5) + (x >> 2);
    float v = BSF[base] + Z[base] * a + c0;
    float4 f = ((const float4*)f0)[i4];
    float4 o; o.x = f.x + v; o.y = f.y + v; o.z = f.z + v; o.w = f.w + v;
    ((float4*)out)[i4] = o;
  } else if (i4 < 5242880) {                // f1: 64x64, upsample x2
    const int l4 = i4 - 4194304;
    const int l = l4 << 2;
    const int x = l & 63, yy = (l >> 6) & 63, nc = l >> 12;
    const int ch = nc & 255, b = nc >> 8;
    float2 mv = ST[b * 32 + (ch >> 3)];
    float a = mv.y * gamma[ch];
    float c0 = beta[ch] - mv.x * a;
    size_t base = (size_t)nc * 1024 + ((yy >> 1) << 5) + (x >> 1);
    float v0 = BSF[base] + Z[base] * a + c0;
    float v1 = BSF[base + 1] + Z[base + 1] * a + c0;
    float4 f = ((const float4*)f1)[l4];
    float4 o; o.x = f.x + v0; o.y = f.y + v0; o.z = f.z + v1; o.w = f.w + v1;
    ((float4*)out)[i4] = o;
  } else if (i4 < 5505024) {                // f2: 32x32, identity
    const int l4 = i4 - 5242880;
    const int l = l4 << 2;
    const int nc = l >> 10, e = l & 1023;
    const int ch = nc & 255, b = nc >> 8;
    float2 mv = ST[b * 32 + (ch >> 3)];
    float a = mv.y * gamma[ch];
    float c0 = beta[ch] - mv.x * a;
    size_t base = (size_t)nc * 1024 + e;
    float4 z4 = *(const float4*)&Z[base];
    float4 b4 = *(const float4*)&BSF[base];
    float4 v = gmix(b4, z4, a, c0);
    float4 f = ((const float4*)f2)[l4];
    float4 o; o.x = f.x + v.x; o.y = f.y + v.y; o.z = f.z + v.z; o.w = f.w + v.w;
    ((float4*)out)[i4] = o;
  } else if (i4 < 5570560) {                // f3: 16x16, maxpool 2x2
    const int l4 = i4 - 5505024;
    const int l = l4 << 2;
    const int x = l & 15, yy = (l >> 4) & 15, nc = l >> 8;
    const int ch = nc & 255, b = nc >> 8;
    float2 mv = ST[b * 32 + (ch >> 3)];
    float a = mv.y * gamma[ch];
    float c0 = beta[ch] - mv.x * a;
    size_t base = (size_t)nc * 1024;
    const int p0 = (yy * 2) * 32 + (x * 2);
    float4 r0a = gmix(*(const float4*)&BSF[base + p0],      *(const float4*)&Z[base + p0],      a, c0);
    float4 r0b = gmix(*(const float4*)&BSF[base + p0 + 4],  *(const float4*)&Z[base + p0 + 4],  a, c0);
    float4 r1a = gmix(*(const float4*)&BSF[base + p0 + 32], *(const float4*)&Z[base + p0 + 32], a, c0);
    float4 r1b = gmix(*(const float4*)&BSF[base + p0 + 36], *(const float4*)&Z[base + p0 + 36], a, c0);
    float4 f = ((const float4*)f3)[l4];
    float4 o;
    o.x = f.x + fmaxf(fmaxf(r0a.x, r0a.y), fmaxf(r1a.x, r1a.y));
    o.y = f.y + fmaxf(fmaxf(r0a.z, r0a.w), fmaxf(r1a.z, r1a.w));
    o.z = f.z + fmaxf(fmaxf(r0b.x, r0b.y), fmaxf(r1b.x, r1b.y));
    o.w = f.w + fmaxf(fmaxf(r0b.z, r0b.w), fmaxf(r1b.z, r1b.w));
    ((float4*)out)[i4] = o;
  } else {                                   // f4: 8x8, maxpool 4x4
    const int l4 = i4 - 5570560;
    const int l = l4 << 2;
    const int x = l & 7, yy = (l >> 3) & 7, nc = l >> 6;
    const int ch = nc & 255, b = nc >> 8;
    float2 mv = ST[b * 32 + (ch >> 3)];
    float a = mv.y * gamma[ch];
    float c0 = beta[ch] - mv.x * a;
    size_t base = (size_t)nc * 1024;
    float4 mx = {-3.4e38f, -3.4e38f, -3.4e38f, -3.4e38f};
#pragma unroll
    for (int r = 0; r < 4; ++r) {
      const float* zp = &Z[base + (size_t)(yy * 4 + r) * 32 + x * 4];
      const float* bp = &BSF[base + (size_t)(yy * 4 + r) * 32 + x * 4];
      float4 q0 = gmix(*(const float4*)(bp),      *(const float4*)(zp),      a, c0);
      float4 q1 = gmix(*(const float4*)(bp + 4),  *(const float4*)(zp + 4),  a, c0);
      float4 q2 = gmix(*(const float4*)(bp + 8),  *(const float4*)(zp + 8),  a, c0);
      float4 q3 = gmix(*(const float4*)(bp + 12), *(const float4*)(zp + 12), a, c0);
      mx.x = fmaxf(mx.x, max4(q0));
      mx.y = fmaxf(mx.y, max4(q1));
      mx.z = fmaxf(mx.z, max4(q2));
      mx.w = fmaxf(mx.w, max4(q3));
    }
    float4 f = ((const float4*)f4)[l4];
    float4 o; o.x = f.x + mx.x; o.y = f.y + mx.y; o.z = f.z + mx.z; o.w = f.w + mx.w;
    ((float4*)out)[i4] = o;
  }
}

// ---------------------------------------------------------------------------
extern "C" void kernel_launch(void* const* d_in, const int* in_sizes, int n_in,
                              void* d_out, int out_size, void* d_ws, size_t ws_size,
                              hipStream_t stream)
{
  (void)in_sizes; (void)n_in; (void)out_size; (void)ws_size;
  const float* f0   = (const float*)d_in[0];
  const float* f1   = (const float*)d_in[1];
  const float* f2   = (const float*)d_in[2];
  const float* f3   = (const float*)d_in[3];
  const float* f4   = (const float*)d_in[4];
  const float* g_w  = (const float*)d_in[5];
  const float* g_b  = (const float*)d_in[6];
  const float* th_w = (const float*)d_in[7];
  const float* th_b = (const float*)d_in[8];
  const float* ph_w = (const float*)d_in[9];
  const float* ph_b = (const float*)d_in[10];
  const float* ow_w = (const float*)d_in[11];
  const float* ow_b = (const float*)d_in[12];
  const float* gn_g = (const float*)d_in[13];
  const float* gn_b = (const float*)d_in[14];
  char* ws = (char*)d_ws;

  // 1) gather + weight prep (independent roles, one launch)
  prep_k<<<311, 256, 0, stream>>>(f0, f1, f2, f3, f4,
                                  g_w, ph_w, th_w, ow_w,
                                  g_b, ph_b, th_b, ws);
  // 2) persistent middle: S -> T0 -> Mth -> z(+GN stats) with grid barriers
  middle_k<<<256, 256, 0, stream>>>(ws, ow_b);
  // 3) fused GN-normalize + residual scatter
  scat_k<<<21824, 256, 0, stream>>>(ws, f0, f1, f2, f3, f4, gn_g, gn_b,
                                    (float*)d_out);
}

// Round 3
// 161.988 us; speedup vs baseline: 2.1165x; 1.9333x over previous
//
#include <hip/hip_runtime.h>

typedef __bf16 bf16x8 __attribute__((ext_vector_type(8)));
typedef float f32x4 __attribute__((ext_vector_type(4)));

// ---------------------------------------------------------------------------
// Workspace layout (bytes):
#define OFF_BSF   0x000000   // f32  [4][256][1024]  4 MB
#define OFF_BSFT  0x400000   // bf16 [4][1024][256]  2 MB   (spatial-major)
#define OFF_BSFB  0x600000   // bf16 [4][256][1024]  2 MB   (channel-major)
#define OFF_Z     0x800000   // f32  [4][256][1024]  4 MB
#define OFF_SBH   0xC00000   // bf16 [4][256][256]   512 KB  S hi
#define OFF_SBL   0xC80000   // bf16 [4][256][256]   512 KB  S lo (residual)
#define OFF_T0    0xD00000   // bf16 [4][256][256]   T0 = U*S
#define OFF_MTH   0xD80000   // bf16 [4][256][256]   Mth
#define OFF_OWB   0xE00000   // bf16 [256][256]
#define OFF_GWT   0xE20000   // bf16 g_w^T
#define OFF_PHT   0xE40000   // bf16 ph_w^T
#define OFF_THT   0xE60000   // bf16 th_w^T
#define OFF_UB    0xE80000   // bf16 U = ow*g_w
#define OFF_VB    0xEA0000   // bf16 V = ph_w^T*th_w
#define OFF_VTB   0xEC0000   // bf16 V^T
#define OFF_RPART 0xEE0000   // f32 [16][1024] row-sum partials
#define OFF_R     0xEF0000   // f32 [4][256]  r = bsf.1
#define OFF_UV    0xEF1000   // f32 [256]  u = ow*g_b
#define OFF_V2    0xEF1400   // f32 [256]  v2 = ph_w^T*th_b
#define OFF_W2    0xEF1800   // f32 [256]  w2 = th_w^T*ph_b
#define OFF_S2    0xEF1C00   // f32 s2 = ph_b.th_b
#define OFF_RV2   0xEF1C40   // f32 [4]  r.v2
#define OFF_CVEC  0xEF2000   // f32 [4][256]  U*r
#define OFF_GVEC  0xEF3000   // f32 [4][256]  (V^T r)/N + w2
#define OFF_QV    0xEF4000   // f32 [4][256]  per-channel constant of z
#define OFF_STATS 0xEF9000   // f32 [4][32][2] RAW (sum, sumsq) via atomics
#define OFF_ARR   0xEFA000   // u32 [256][16] per-block arrive flags (64B apart)
#define OFF_REL   0xEFE000   // u32 release flag
// ---------------------------------------------------------------------------

// ---------------- prep: gather + weight cvt/transpose + bias matvecs --------
__global__ __launch_bounds__(256) void prep_k(
    const float* __restrict__ f0, const float* __restrict__ f1,
    const float* __restrict__ f2, const float* __restrict__ f3,
    const float* __restrict__ f4,
    const float* __restrict__ g_w, const float* __restrict__ ph_w,
    const float* __restrict__ th_w, const float* __restrict__ ow_w,
    const float* __restrict__ g_b, const float* __restrict__ ph_b,
    const float* __restrict__ th_b,
    char* __restrict__ ws)
{
  const int blk = blockIdx.x, t = threadIdx.x;
  __shared__ __attribute__((aligned(16))) union {
    __bf16 Lt[64][66];
    __bf16 T[64][72];
    float vec[256];
  } sm;

  if (blk < 256) {
    // ---- gather: bsf fp32 + bsfB bf16 (ch-major) + bsfT bf16 (sp-major) + rowsum partials
    float*  bsf   = (float*)(ws + OFF_BSF);
    __bf16* bsfT  = (__bf16*)(ws + OFF_BSFT);
    __bf16* bsfB  = (__bf16*)(ws + OFF_BSFB);
    float*  rpart = (float*)(ws + OFF_RPART);
    const int sblk = blk & 15, cblk = (blk >> 4) & 3, b = blk >> 6;
    const int c0 = cblk * 64, s0 = sblk * 64;
    const int spl = t & 63, sp = s0 + spl;
    const int y = sp >> 5, x = sp & 31;
#pragma unroll
    for (int i = 0; i < 16; ++i) {
      const int cl = (t >> 6) + i * 4;
      const int nc = b * 256 + c0 + cl;

      const float* p0 = f0 + (size_t)nc * 16384 + (y * 4) * 128 + x * 4;
      float4 r0 = *(const float4*)(p0);
      float4 r1 = *(const float4*)(p0 + 128);
      float4 r2 = *(const float4*)(p0 + 256);
      float4 r3 = *(const float4*)(p0 + 384);
      float a  = fmaxf(fmaxf(r0.x, r0.y), fmaxf(r0.z, r0.w));
      float bb = fmaxf(fmaxf(r1.x, r1.y), fmaxf(r1.z, r1.w));
      float c  = fmaxf(fmaxf(r2.x, r2.y), fmaxf(r2.z, r2.w));
      float d  = fmaxf(fmaxf(r3.x, r3.y), fmaxf(r3.z, r3.w));
      float m0v = fmaxf(fmaxf(a, bb), fmaxf(c, d));

      const float* p1 = f1 + (size_t)nc * 4096 + (y * 2) * 64 + x * 2;
      float2 s0v = *(const float2*)(p1);
      float2 s1v = *(const float2*)(p1 + 64);
      float m1v = fmaxf(fmaxf(s0v.x, s0v.y), fmaxf(s1v.x, s1v.y));

      float v2 = f2[(size_t)nc * 1024 + sp];
      float v3 = f3[(size_t)nc * 256 + (y >> 1) * 16 + (x >> 1)];
      float v4 = f4[(size_t)nc * 64  + (y >> 2) * 8  + (x >> 2)];
      float val = (m0v + m1v + v2 + v3 + v4) * 0.2f;
      bsf[(size_t)nc * 1024 + sp]  = val;
      bsfB[(size_t)nc * 1024 + sp] = (__bf16)val;
      sm.Lt[cl][spl] = (__bf16)val;
      float rs = val;
#pragma unroll
      for (int off = 32; off; off >>= 1) rs += __shfl_down(rs, off);
      if (spl == 0) rpart[sblk * 1024 + nc] = rs;
    }
    __syncthreads();
#pragma unroll
    for (int i = 0; i < 16; ++i) {
      int linear = t + i * 256;
      int spl2 = linear >> 6, cl2 = linear & 63;
      bsfT[((size_t)b * 1024 + s0 + spl2) * 256 + c0 + cl2] = sm.Lt[cl2][spl2];
    }
  } else if (blk < 304) {
    // ---- weight transposes (fp32 -> bf16): gwT/phT/thT, 64x64 tiles
    const int w = (blk - 256) >> 4, tl = (blk - 256) & 15;
    const float* src = (w == 0) ? g_w : (w == 1) ? ph_w : th_w;
    __bf16* dst = (__bf16*)(ws + ((w == 0) ? OFF_GWT : (w == 1) ? OFF_PHT : OFF_THT));
    const int ti = (tl >> 2) * 64, tj = (tl & 3) * 64;
#pragma unroll
    for (int i = 0; i < 4; ++i) {
      int idx = i * 256 + t;
      int r = idx >> 4, c4 = (idx & 15) << 2;
      float4 v = *(const float4*)&src[(size_t)(ti + r) * 256 + tj + c4];
      sm.T[c4 + 0][r] = (__bf16)v.x;
      sm.T[c4 + 1][r] = (__bf16)v.y;
      sm.T[c4 + 2][r] = (__bf16)v.z;
      sm.T[c4 + 3][r] = (__bf16)v.w;
    }
    __syncthreads();
#pragma unroll
    for (int i = 0; i < 2; ++i) {
      int idx = i * 256 + t;
      int aa = idx >> 3, cc = (idx & 7) << 3;
      bf16x8 o = *(const bf16x8*)&sm.T[aa][cc];
      *(bf16x8*)&dst[(size_t)(tj + aa) * 256 + ti + cc] = o;
    }
  } else if (blk < 308) {
    // ---- owB plain convert
    const int r0 = (blk - 304) * 64;
    __bf16* owB = (__bf16*)(ws + OFF_OWB);
#pragma unroll
    for (int i = 0; i < 8; ++i) {
      int lin = i * 2048 + t * 8;
      size_t gidx = (size_t)r0 * 256 + lin;
      float4 v0 = *(const float4*)&ow_w[gidx];
      float4 v1 = *(const float4*)&ow_w[gidx + 4];
      bf16x8 o;
      o[0] = (__bf16)v0.x; o[1] = (__bf16)v0.y; o[2] = (__bf16)v0.z; o[3] = (__bf16)v0.w;
      o[4] = (__bf16)v1.x; o[5] = (__bf16)v1.y; o[6] = (__bf16)v1.z; o[7] = (__bf16)v1.w;
      *(bf16x8*)&owB[gidx] = o;
    }
  } else if (blk == 308) {
    // ---- u = ow_w . g_b ; zero barrier flags + raw GN stats
    float* uv = (float*)(ws + OFF_UV);
    sm.vec[t] = g_b[t];
    __syncthreads();
    const int wv = t >> 6, l = t & 63;
    for (int rr = 0; rr < 64; ++rr) {
      int row = wv * 64 + rr;
      const float* p = ow_w + (size_t)row * 256;
      float pa = p[l] * sm.vec[l] + p[64 + l] * sm.vec[64 + l]
               + p[128 + l] * sm.vec[128 + l] + p[192 + l] * sm.vec[192 + l];
#pragma unroll
      for (int off = 32; off; off >>= 1) pa += __shfl_down(pa, off);
      if (l == 0) uv[row] = pa;
    }
    unsigned* arr = (unsigned*)(ws + OFF_ARR);
#pragma unroll
    for (int i = 0; i < 16; ++i) arr[t * 16 + i] = 0u;
    if (t == 0) *(unsigned*)(ws + OFF_REL) = 0u;
    ((float*)(ws + OFF_STATS))[t] = 0.f;
  } else if (blk == 309) {
    // ---- v2 = ph_w^T . th_b (column dot, coalesced) ; s2 = ph_b.th_b
    float* v2 = (float*)(ws + OFF_V2);
    float* s2 = (float*)(ws + OFF_S2);
    float acc = 0.f;
#pragma unroll 8
    for (int c = 0; c < 256; ++c) acc += ph_w[(size_t)c * 256 + t] * th_b[c];
    v2[t] = acc;
    if (t < 64) {
      float pa = ph_b[t] * th_b[t] + ph_b[64 + t] * th_b[64 + t]
               + ph_b[128 + t] * th_b[128 + t] + ph_b[192 + t] * th_b[192 + t];
#pragma unroll
      for (int off = 32; off; off >>= 1) pa += __shfl_down(pa, off);
      if (t == 0) s2[0] = pa;
    }
  } else {
    // ---- w2 = th_w^T . ph_b
    float* w2 = (float*)(ws + OFF_W2);
    float acc = 0.f;
#pragma unroll 8
    for (int c = 0; c < 256; ++c) acc += th_w[(size_t)c * 256 + t] * ph_b[c];
    w2[t] = acc;
  }
}

// ---------------- GEMM accumulate core (64x64 tile, 4 waves, dbuf) ----------
__device__ __forceinline__ void gemm_acc(
    const __bf16* __restrict__ A, const __bf16* __restrict__ B,
    const int K, const int m0, const int n0,
    __bf16 (*Al)[64][72], __bf16 (*Bl)[64][72],
    f32x4 acc[2][2])
{
  const int t = threadIdx.x;
  const int lane = t & 63, wv = t >> 6;
  const int wm = (wv & 1) * 32, wn = (wv >> 1) * 32;
  const int fr = lane & 15, lk = (lane >> 4) * 8;
  const int sr = t >> 2, sk = (t & 3) * 16;

  const __bf16* Ar = A + (size_t)(m0 + sr) * K + sk;
  const __bf16* Br = B + (size_t)(n0 + sr) * K + sk;

  bf16x8 ra0 = *(const bf16x8*)(Ar);
  bf16x8 ra1 = *(const bf16x8*)(Ar + 8);
  bf16x8 rb0 = *(const bf16x8*)(Br);
  bf16x8 rb1 = *(const bf16x8*)(Br + 8);

  const int nIter = K >> 6;
  int p = 0;
  for (int it = 0; it < nIter; ++it) {
    *(bf16x8*)&Al[p][sr][sk]     = ra0;
    *(bf16x8*)&Al[p][sr][sk + 8] = ra1;
    *(bf16x8*)&Bl[p][sr][sk]     = rb0;
    *(bf16x8*)&Bl[p][sr][sk + 8] = rb1;
    __syncthreads();
    if (it + 1 < nIter) {
      const __bf16* An = Ar + (size_t)(it + 1) * 64;
      const __bf16* Bn = Br + (size_t)(it + 1) * 64;
      ra0 = *(const bf16x8*)(An);
      ra1 = *(const bf16x8*)(An + 8);
      rb0 = *(const bf16x8*)(Bn);
      rb1 = *(const bf16x8*)(Bn + 8);
    }
#pragma unroll
    for (int kk = 0; kk < 64; kk += 32) {
      bf16x8 a0 = *(const bf16x8*)&Al[p][wm + fr][kk + lk];
      bf16x8 a1 = *(const bf16x8*)&Al[p][wm + 16 + fr][kk + lk];
      bf16x8 b0 = *(const bf16x8*)&Bl[p][wn + fr][kk + lk];
      bf16x8 b1 = *(const bf16x8*)&Bl[p][wn + 16 + fr][kk + lk];
      acc[0][0] = __builtin_amdgcn_mfma_f32_16x16x32_bf16(a0, b0, acc[0][0], 0, 0, 0);
      acc[0][1] = __builtin_amdgcn_mfma_f32_16x16x32_bf16(a0, b1, acc[0][1], 0, 0, 0);
      acc[1][0] = __builtin_amdgcn_mfma_f32_16x16x32_bf16(a1, b0, acc[1][0], 0, 0, 0);
      acc[1][1] = __builtin_amdgcn_mfma_f32_16x16x32_bf16(a1, b1, acc[1][1], 0, 0, 0);
    }
    __syncthreads();
    p ^= 1;
  }
}

__device__ __forceinline__ void store_bf16(
    __bf16* dst, int ldst, const f32x4 acc[2][2],
    int m0, int n0, int wm, int wn, int rbase, int fr)
{
#pragma unroll
  for (int i = 0; i < 2; ++i)
#pragma unroll
    for (int r = 0; r < 4; ++r) {
      int m = m0 + wm + i * 16 + rbase + r;
#pragma unroll
      for (int j = 0; j < 2; ++j) {
        int n = n0 + wn + j * 16 + fr;
        dst[(size_t)m * ldst + n] = (__bf16)acc[i][j][r];
      }
    }
}

// ---------------- software grid barrier, v3 ---------------------------------
// Round-1/2 lesson: per-WAVE __threadfence (s_waitcnt + L2 writeback) x 1024
// waves x 2 x 4 barriers was the dominant cost (~57us/barrier), and the
// single-line atomicAdd chain added contention. v3:
//  - one release fence (wbl2) per BLOCK (thread 0; __syncthreads already
//    drained every wave's vmcnt, so all stores are in L2 first),
//  - arrival = plain agent-scope store to the block's own 64B-spaced flag,
//  - block 0's 256 threads poll the 256 distinct flag lines, then publish
//    one release flag; other blocks poll only that (s_sleep backoff),
//  - acquire = flash-invalidate fence, once per block.
__device__ __forceinline__ void gsync(char* __restrict__ ws, int p)
{
  unsigned* arr = (unsigned*)(ws + OFF_ARR);
  unsigned* rel = (unsigned*)(ws + OFF_REL);
  const int t = threadIdx.x;
  __syncthreads();                 // drains vmcnt/lgkm for every wave
  if (blockIdx.x == 0) {
    if (t == 0) __builtin_amdgcn_fence(__ATOMIC_RELEASE, "agent");
    __syncthreads();
    if (t > 0) {
      while (__hip_atomic_load(&arr[t * 16], __ATOMIC_RELAXED,
                               __HIP_MEMORY_SCOPE_AGENT) < (unsigned)p)
        __builtin_amdgcn_s_sleep(4);
    }
    __syncthreads();
    if (t == 0) {
      __hip_atomic_store(rel, (unsigned)p, __ATOMIC_RELAXED,
                         __HIP_MEMORY_SCOPE_AGENT);
      __builtin_amdgcn_fence(__ATOMIC_ACQUIRE, "agent");
    }
    __syncthreads();
  } else {
    if (t == 0) {
      __builtin_amdgcn_fence(__ATOMIC_RELEASE, "agent");
      __hip_atomic_store(&arr[blockIdx.x * 16], (unsigned)p, __ATOMIC_RELAXED,
                         __HIP_MEMORY_SCOPE_AGENT);
      while (__hip_atomic_load(rel, __ATOMIC_RELAXED,
                               __HIP_MEMORY_SCOPE_AGENT) < (unsigned)p)
        __builtin_amdgcn_s_sleep(16);
      __builtin_amdgcn_fence(__ATOMIC_ACQUIRE, "agent");
    }
    __syncthreads();
  }
}

// ---------------- persistent middle kernel ----------------------------------
// P0: S = bsf.bsf^T (hi/lo bf16) ; U = ow*g_w ; V = ph_w^T*th_w ; r finalize
// P1: T0 = U*S (split-compensated) ; cvec = U*r ; gvec = (V^T r)/N + w2 ; rv2
// P2: Mth = T0*V/N + rank-1 bias terms ; qv = per-channel const of z
// P3: z = Mth*bsf + qv ; GN raw stats via global atomics (no 4th barrier)
__global__ __launch_bounds__(256) void middle_k(char* __restrict__ ws,
                                                const float* __restrict__ ow_b)
{
  const int blk = blockIdx.x, t = threadIdx.x;
  __shared__ __attribute__((aligned(16))) __bf16 Al[2][64][72];
  __shared__ __attribute__((aligned(16))) __bf16 Bl[2][64][72];
  float* shf = (float*)(&Al[0][0][0]);

  const int lane = t & 63, wv = t >> 6;
  const int wm = (wv & 1) * 32, wn = (wv >> 1) * 32;
  const int fr = lane & 15;
  const int rbase = (lane >> 4) * 4;

  const __bf16* bsfB = (const __bf16*)(ws + OFF_BSFB);
  const __bf16* bsfT = (const __bf16*)(ws + OFF_BSFT);
  __bf16* SBh  = (__bf16*)(ws + OFF_SBH);
  __bf16* SBl  = (__bf16*)(ws + OFF_SBL);
  __bf16* T0B  = (__bf16*)(ws + OFF_T0);
  __bf16* MthB = (__bf16*)(ws + OFF_MTH);
  const __bf16* owB = (const __bf16*)(ws + OFF_OWB);
  const __bf16* gwT = (const __bf16*)(ws + OFF_GWT);
  const __bf16* phT = (const __bf16*)(ws + OFF_PHT);
  const __bf16* thT = (const __bf16*)(ws + OFF_THT);
  __bf16* UB  = (__bf16*)(ws + OFF_UB);
  __bf16* VB  = (__bf16*)(ws + OFF_VB);
  __bf16* VTB = (__bf16*)(ws + OFF_VTB);
  float* Z  = (float*)(ws + OFF_Z);
  float* Rr = (float*)(ws + OFF_R);
  const float* rpart = (const float*)(ws + OFF_RPART);
  const float* uv  = (const float*)(ws + OFF_UV);
  const float* v2f = (const float*)(ws + OFF_V2);
  const float* w2f = (const float*)(ws + OFF_W2);
  const float* s2f = (const float*)(ws + OFF_S2);
  float* rv2  = (float*)(ws + OFF_RV2);
  float* cvec = (float*)(ws + OFF_CVEC);
  float* gvec = (float*)(ws + OFF_GVEC);
  float* qv   = (float*)(ws + OFF_QV);
  float* SRAW = (float*)(ws + OFF_STATS);

  // ---------------- P0 ----------------
  if (blk < 64) {
    const int b = blk >> 4, tl = blk & 15;
    const int m0 = (tl >> 2) * 64, n0 = (tl & 3) * 64;
    f32x4 acc[2][2];
#pragma unroll
    for (int i = 0; i < 2; ++i)
#pragma unroll
      for (int j = 0; j < 2; ++j) acc[i][j] = (f32x4){0.f, 0.f, 0.f, 0.f};
    gemm_acc(bsfB + (size_t)b * 262144, bsfB + (size_t)b * 262144, 1024, m0, n0, Al, Bl, acc);
    __bf16* oh = SBh + (size_t)b * 65536;
    __bf16* ol = SBl + (size_t)b * 65536;
#pragma unroll
    for (int i = 0; i < 2; ++i)
#pragma unroll
      for (int r = 0; r < 4; ++r) {
        int m = m0 + wm + i * 16 + rbase + r;
#pragma unroll
        for (int j = 0; j < 2; ++j) {
          int n = n0 + wn + j * 16 + fr;
          float v = acc[i][j][r];
          __bf16 h = (__bf16)v;
          oh[(size_t)m * 256 + n] = h;
          ol[(size_t)m * 256 + n] = (__bf16)(v - (float)h);
        }
      }
  } else if (blk < 80) {
    const int tl = blk - 64;
    const int m0 = (tl >> 2) * 64, n0 = (tl & 3) * 64;
    f32x4 acc[2][2];
#pragma unroll
    for (int i = 0; i < 2; ++i)
#pragma unroll
      for (int j = 0; j < 2; ++j) acc[i][j] = (f32x4){0.f, 0.f, 0.f, 0.f};
    gemm_acc(owB, gwT, 256, m0, n0, Al, Bl, acc);
    store_bf16(UB, 256, acc, m0, n0, wm, wn, rbase, fr);
  } else if (blk < 96) {
    const int tl = blk - 80;
    const int m0 = (tl >> 2) * 64, n0 = (tl & 3) * 64;
    f32x4 acc[2][2];
#pragma unroll
    for (int i = 0; i < 2; ++i)
#pragma unroll
      for (int j = 0; j < 2; ++j) acc[i][j] = (f32x4){0.f, 0.f, 0.f, 0.f};
    gemm_acc(phT, thT, 256, m0, n0, Al, Bl, acc);
#pragma unroll
    for (int i = 0; i < 2; ++i)
#pragma unroll
      for (int r = 0; r < 4; ++r) {
        int m = m0 + wm + i * 16 + rbase + r;
#pragma unroll
        for (int j = 0; j < 2; ++j) {
          int n = n0 + wn + j * 16 + fr;
          __bf16 v = (__bf16)acc[i][j][r];
          VB[(size_t)m * 256 + n] = v;
          VTB[(size_t)n * 256 + m] = v;
        }
      }
  } else if (blk == 96) {
#pragma unroll
    for (int j2 = 0; j2 < 4; ++j2) {
      int idx = t + j2 * 256;
      float s = 0.f;
#pragma unroll
      for (int k = 0; k < 16; ++k) s += rpart[k * 1024 + idx];
      Rr[idx] = s;
    }
  }
  gsync(ws, 1);

  // ---------------- P1 ----------------
  if (blk < 64) {
    const int b = blk >> 4, tl = blk & 15;
    const int m0 = (tl >> 2) * 64, n0 = (tl & 3) * 64;
    f32x4 acc[2][2];
#pragma unroll
    for (int i = 0; i < 2; ++i)
#pragma unroll
      for (int j = 0; j < 2; ++j) acc[i][j] = (f32x4){0.f, 0.f, 0.f, 0.f};
    gemm_acc(UB, SBh + (size_t)b * 65536, 256, m0, n0, Al, Bl, acc);
    gemm_acc(UB, SBl + (size_t)b * 65536, 256, m0, n0, Al, Bl, acc);
    store_bf16(T0B + (size_t)b * 65536, 256, acc, m0, n0, wm, wn, rbase, fr);
  } else if (blk < 80) {
    const int q = blk - 64;
    const int b = q >> 2, r0 = (q & 3) * 64;
    shf[t] = Rr[b * 256 + t];
    __syncthreads();
    for (int rr = 0; rr < 16; ++rr) {
      int row = r0 + wv * 16 + rr;
      const __bf16* p = UB + (size_t)row * 256;
      float pa = (float)p[lane] * shf[lane] + (float)p[64 + lane] * shf[64 + lane]
               + (float)p[128 + lane] * shf[128 + lane] + (float)p[192 + lane] * shf[192 + lane];
#pragma unroll
      for (int off = 32; off; off >>= 1) pa += __shfl_down(pa, off);
      if (lane == 0) cvec[b * 256 + row] = pa;
    }
  } else if (blk < 84) {
    const int b = blk - 80;
    shf[t] = Rr[b * 256 + t];
    __syncthreads();
    float acc2 = 0.f;
#pragma unroll 8
    for (int c2 = 0; c2 < 256; ++c2) acc2 += (float)VB[(size_t)c2 * 256 + t] * shf[c2];
    gvec[b * 256 + t] = acc2 * (1.f / 1024.f) + w2f[t];
  } else if (blk == 84) {
    float pa = Rr[wv * 256 + lane] * v2f[lane]
             + Rr[wv * 256 + 64 + lane] * v2f[64 + lane]
             + Rr[wv * 256 + 128 + lane] * v2f[128 + lane]
             + Rr[wv * 256 + 192 + lane] * v2f[192 + lane];
#pragma unroll
    for (int off = 32; off; off >>= 1) pa += __shfl_down(pa, off);
    if (lane == 0) rv2[wv] = pa;
  }
  gsync(ws, 2);

  // ---------------- P2 ----------------
  if (blk < 64) {
    const int b = blk >> 4, tl = blk & 15;
    const int m0 = (tl >> 2) * 64, n0 = (tl & 3) * 64;
    f32x4 acc[2][2];
#pragma unroll
    for (int i = 0; i < 2; ++i)
#pragma unroll
      for (int j = 0; j < 2; ++j) acc[i][j] = (f32x4){0.f, 0.f, 0.f, 0.f};
    gemm_acc(T0B + (size_t)b * 65536, VTB, 256, m0, n0, Al, Bl, acc);
    const float s1024 = 1.f / 1024.f;
    __bf16* od = MthB + (size_t)b * 65536;
#pragma unroll
    for (int i = 0; i < 2; ++i)
#pragma unroll
      for (int r = 0; r < 4; ++r) {
        int m = m0 + wm + i * 16 + rbase + r;
        float um = uv[m], cv = cvec[b * 256 + m];
#pragma unroll
        for (int j = 0; j < 2; ++j) {
          int n = n0 + wn + j * 16 + fr;
          float val = acc[i][j][r] * s1024 + um * gvec[b * 256 + n] + cv * w2f[n] * s1024;
          od[(size_t)m * 256 + n] = (__bf16)val;
        }
      }
  } else if (blk < 68) {
    const int b = blk - 64;
    shf[t] = v2f[t];
    __syncthreads();
    const float rvb = rv2[b], s2v = s2f[0];
    for (int rr = 0; rr < 64; ++rr) {
      int row = wv * 64 + rr;
      const __bf16* p = T0B + (size_t)b * 65536 + (size_t)row * 256;
      float pa = (float)p[lane] * shf[lane] + (float)p[64 + lane] * shf[64 + lane]
               + (float)p[128 + lane] * shf[128 + lane] + (float)p[192 + lane] * shf[192 + lane];
#pragma unroll
      for (int off = 32; off; off >>= 1) pa += __shfl_down(pa, off);
      if (lane == 0)
        qv[b * 256 + row] = pa * (1.f / 1024.f)
                          + uv[row] * (rvb * (1.f / 1024.f) + s2v)
                          + cvec[b * 256 + row] * s2v * (1.f / 1024.f)
                          + ow_b[row];
    }
  }
  gsync(ws, 3);

  // ---------------- P3: z = Mth*bsf + qv, GN raw stats via atomics ----------
  {
    const int b = blk >> 6, t6 = blk & 63;
    const int mt = t6 >> 4, nt = t6 & 15;
    const int m0 = mt * 64, n0 = nt * 64;
    (void)nt;
    f32x4 acc[2][2];
#pragma unroll
    for (int i = 0; i < 2; ++i)
#pragma unroll
      for (int j = 0; j < 2; ++j) acc[i][j] = (f32x4){0.f, 0.f, 0.f, 0.f};
    gemm_acc(MthB + (size_t)b * 65536, bsfT + (size_t)b * 262144, 256, m0, n0, Al, Bl, acc);

    float gs[2] = {0.f, 0.f}, gq[2] = {0.f, 0.f};
    int gidx[2];
    float* zb = Z + (size_t)b * 262144;
#pragma unroll
    for (int i = 0; i < 2; ++i) {
      gidx[i] = (wm + i * 16 + rbase) >> 3;
#pragma unroll
      for (int r = 0; r < 4; ++r) {
        int m = m0 + wm + i * 16 + rbase + r;
        float qm = qv[b * 256 + m];
#pragma unroll
        for (int j = 0; j < 2; ++j) {
          int n = n0 + wn + j * 16 + fr;
          float v = acc[i][j][r] + qm;
          zb[(size_t)m * 1024 + n] = v;
          gs[i] += v;
          gq[i] += v * v;
        }
      }
    }
    __syncthreads();
    if (t < 16) shf[t] = 0.f;
    __syncthreads();
#pragma unroll
    for (int i = 0; i < 2; ++i) {
      atomicAdd(&shf[gidx[i] * 2], gs[i]);
      atomicAdd(&shf[gidx[i] * 2 + 1], gq[i]);
    }
    __syncthreads();
    if (t < 16) {
      int g = mt * 8 + (t >> 1);
      atomicAdd(&SRAW[(b * 32 + g) * 2 + (t & 1)], shf[t]);
    }
  }
}

// ---------------- fused GN + residual scatter (float4) ----------------------
__device__ __forceinline__ float4 gmix(float4 bz, float4 zz, float a, float c)
{
  float4 r;
  r.x = bz.x + zz.x * a + c;
  r.y = bz.y + zz.y * a + c;
  r.z = bz.z + zz.z * a + c;
  r.w = bz.w + zz.w * a + c;
  return r;
}
__device__ __forceinline__ float max4(float4 v)
{ return fmaxf(fmaxf(v.x, v.y), fmaxf(v.z, v.w)); }

// raw (sum, sumsq) -> (a = inv*gamma, c0 = beta - mean*a)
__device__ __forceinline__ void gn_coeff(const float2* __restrict__ ST,
                                         const float* __restrict__ gamma,
                                         const float* __restrict__ beta,
                                         int b, int ch, float& a, float& c0)
{
  float2 sq = ST[b * 32 + (ch >> 3)];
  float mean = sq.x * (1.0f / 8192.0f);
  float var  = sq.y * (1.0f / 8192.0f) - mean * mean;
  float inv  = rsqrtf(var + 1e-5f);
  a  = inv * gamma[ch];
  c0 = beta[ch] - mean * a;
}

__global__ __launch_bounds__(256) void scat_k(
    const char* __restrict__ ws,
    const float* __restrict__ f0, const float* __restrict__ f1,
    const float* __restrict__ f2, const float* __restrict__ f3,
    const float* __restrict__ f4,
    const float* __restrict__ gamma, const float* __restrict__ beta,
    float* __restrict__ out)
{
  const float* Z = (const float*)(ws + OFF_Z);
  const float* BSF = (const float*)(ws + OFF_BSF);
  const float2* ST = (const float2*)(ws + OFF_STATS);
  const int i4 = blockIdx.x * 256 + threadIdx.x;

  if (i4 < 4194304) {                       // f0: 128x128, upsample x4
    const int l = i4 << 2;
    const int x = l & 127, yy = (l >> 7) & 127, nc = l >> 14;
    const int ch = nc & 255, b = nc >> 8;
    float a, c0; gn_coeff(ST, gamma, beta, b, ch, a, c0);
    size_t base = (size_t)nc * 1024 + ((yy >> 2) << 5) + (x >> 2);
    float v = BSF[base] + Z[base] * a + c0;
    float4 f = ((const float4*)f0)[i4];
    float4 o; o.x = f.x + v; o.y = f.y + v; o.z = f.z + v; o.w = f.w + v;
    ((float4*)out)[i4] = o;
  } else if (i4 < 5242880) {                // f1: 64x64, upsample x2
    const int l4 = i4 - 4194304;
    const int l = l4 << 2;
    const int x = l & 63, yy = (l >> 6) & 63, nc = l >> 12;
    const int ch = nc & 255, b = nc >> 8;
    float a, c0; gn_coeff(ST, gamma, beta, b, ch, a, c0);
    size_t base = (size_t)nc * 1024 + ((yy >> 1) << 5) + (x >> 1);
    float v0 = BSF[base] + Z[base] * a + c0;
    float v1 = BSF[base + 1] + Z[base + 1] * a + c0;
    float4 f = ((const float4*)f1)[l4];
    float4 o; o.x = f.x + v0; o.y = f.y + v0; o.z = f.z + v1; o.w = f.w + v1;
    ((float4*)out)[i4] = o;
  } else if (i4 < 5505024) {                // f2: 32x32, identity
    const int l4 = i4 - 5242880;
    const int l = l4 << 2;
    const int nc = l >> 10, e = l & 1023;
    const int ch = nc & 255, b = nc >> 8;
    float a, c0; gn_coeff(ST, gamma, beta, b, ch, a, c0);
    size_t base = (size_t)nc * 1024 + e;
    float4 z4 = *(const float4*)&Z[base];
    float4 b4 = *(const float4*)&BSF[base];
    float4 v = gmix(b4, z4, a, c0);
    float4 f = ((const float4*)f2)[l4];
    float4 o; o.x = f.x + v.x; o.y = f.y + v.y; o.z = f.z + v.z; o.w = f.w + v.w;
    ((float4*)out)[i4] = o;
  } else if (i4 < 5570560) {                // f3: 16x16, maxpool 2x2
    const int l4 = i4 - 5505024;
    const int l = l4 << 2;
    const int x = l & 15, yy = (l >> 4) & 15, nc = l >> 8;
    const int ch = nc & 255, b = nc >> 8;
    float a, c0; gn_coeff(ST, gamma, beta, b, ch, a, c0);
    size_t base = (size_t)nc * 1024;
    const int p0 = (yy * 2) * 32 + (x * 2);
    float4 r0a = gmix(*(const float4*)&BSF[base + p0],      *(const float4*)&Z[base + p0],      a, c0);
    float4 r0b = gmix(*(const float4*)&BSF[base + p0 + 4],  *(const float4*)&Z[base + p0 + 4],  a, c0);
    float4 r1a = gmix(*(const float4*)&BSF[base + p0 + 32], *(const float4*)&Z[base + p0 + 32], a, c0);
    float4 r1b = gmix(*(const float4*)&BSF[base + p0 + 36], *(const float4*)&Z[base + p0 + 36], a, c0);
    float4 f = ((const float4*)f3)[l4];
    float4 o;
    o.x = f.x + fmaxf(fmaxf(r0a.x, r0a.y), fmaxf(r1a.x, r1a.y));
    o.y = f.y + fmaxf(fmaxf(r0a.z, r0a.w), fmaxf(r1a.z, r1a.w));
    o.z = f.z + fmaxf(fmaxf(r0b.x, r0b.y), fmaxf(r1b.x, r1b.y));
    o.w = f.w + fmaxf(fmaxf(r0b.z, r0b.w), fmaxf(r1b.z, r1b.w));
    ((float4*)out)[i4] = o;
  } else {                                   // f4: 8x8, maxpool 4x4
    const int l4 = i4 - 5570560;
    const int l = l4 << 2;
    const int x = l & 7, yy = (l >> 3) & 7, nc = l >> 6;
    const int ch = nc & 255, b = nc >> 8;
    float a, c0; gn_coeff(ST, gamma, beta, b, ch, a, c0);
    size_t base = (size_t)nc * 1024;
    float4 mx = {-3.4e38f, -3.4e38f, -3.4e38f, -3.4e38f};
#pragma unroll
    for (int r = 0; r < 4; ++r) {
      const float* zp = &Z[base + (size_t)(yy * 4 + r) * 32 + x * 4];
      const float* bp = &BSF[base + (size_t)(yy * 4 + r) * 32 + x * 4];
      float4 q0 = gmix(*(const float4*)(bp),      *(const float4*)(zp),      a, c0);
      float4 q1 = gmix(*(const float4*)(bp + 4),  *(const float4*)(zp + 4),  a, c0);
      float4 q2 = gmix(*(const float4*)(bp + 8),  *(const float4*)(zp + 8),  a, c0);
      float4 q3 = gmix(*(const float4*)(bp + 12), *(const float4*)(zp + 12), a, c0);
      mx.x = fmaxf(mx.x, max4(q0));
      mx.y = fmaxf(mx.y, max4(q1));
      mx.z = fmaxf(mx.z, max4(q2));
      mx.w = fmaxf(mx.w, max4(q3));
    }
    float4 f = ((const float4*)f4)[l4];
    float4 o; o.x = f.x + mx.x; o.y = f.y + mx.y; o.z = f.z + mx.z; o.w = f.w + mx.w;
    ((float4*)out)[i4] = o;
  }
}

// ---------------------------------------------------------------------------
extern "C" void kernel_launch(void* const* d_in, const int* in_sizes, int n_in,
                              void* d_out, int out_size, void* d_ws, size_t ws_size,
                              hipStream_t stream)
{
  (void)in_sizes; (void)n_in; (void)out_size; (void)ws_size;
  const float* f0   = (const float*)d_in[0];
  const float* f1   = (const float*)d_in[1];
  const float* f2   = (const float*)d_in[2];
  const float* f3   = (const float*)d_in[3];
  const float* f4   = (const float*)d_in[4];
  const float* g_w  = (const float*)d_in[5];
  const float* g_b  = (const float*)d_in[6];
  const float* th_w = (const float*)d_in[7];
  const float* th_b = (const float*)d_in[8];
  const float* ph_w = (const float*)d_in[9];
  const float* ph_b = (const float*)d_in[10];
  const float* ow_w = (const float*)d_in[11];
  const float* ow_b = (const float*)d_in[12];
  const float* gn_g = (const float*)d_in[13];
  const float* gn_b = (const float*)d_in[14];
  char* ws = (char*)d_ws;

  // 1) gather + weight prep (independent roles, one launch)
  prep_k<<<311, 256, 0, stream>>>(f0, f1, f2, f3, f4,
                                  g_w, ph_w, th_w, ow_w,
                                  g_b, ph_b, th_b, ws);
  // 2) persistent middle: S -> T0 -> Mth -> z(+GN stats), 3 flag barriers
  middle_k<<<256, 256, 0, stream>>>(ws, ow_b);
  // 3) fused GN-normalize + residual scatter (stats finalized inline)
  scat_k<<<21824, 256, 0, stream>>>(ws, f0, f1, f2, f3, f4, gn_g, gn_b,
                                    (float*)d_out);
}

// Round 4
// 150.914 us; speedup vs baseline: 2.2718x; 1.0734x over previous
//
#include <hip/hip_runtime.h>

typedef __bf16 bf16x8 __attribute__((ext_vector_type(8)));
typedef float f32x4 __attribute__((ext_vector_type(4)));

// ---------------------------------------------------------------------------
// Workspace layout (bytes):
#define OFF_BSF   0x000000   // f32  [4][256][1024]  4 MB
#define OFF_BSFT  0x400000   // bf16 [4][1024][256]  2 MB   (spatial-major)
#define OFF_BSFB  0x600000   // bf16 [4][256][1024]  2 MB   (channel-major)
#define OFF_Z     0x800000   // f32  [4][256][1024]  4 MB
#define OFF_SBH   0xC00000   // bf16 [4][256][256]   512 KB  S hi
#define OFF_SBL   0xC80000   // bf16 [4][256][256]   512 KB  S lo (residual)
#define OFF_T0    0xD00000   // bf16 [4][256][256]   T0 = U*S
#define OFF_MTH   0xD80000   // bf16 [4][256][256]   Mth
#define OFF_OWB   0xE00000   // bf16 [256][256]
#define OFF_GWT   0xE20000   // bf16 g_w^T
#define OFF_PHT   0xE40000   // bf16 ph_w^T
#define OFF_THT   0xE60000   // bf16 th_w^T
#define OFF_UB    0xE80000   // bf16 U = ow*g_w
#define OFF_VB    0xEA0000   // bf16 V = ph_w^T*th_w
#define OFF_VTB   0xEC0000   // bf16 V^T
#define OFF_RPART 0xEE0000   // f32 [16][1024] row-sum partials
#define OFF_R     0xEF0000   // f32 [4][256]  r = bsf.1
#define OFF_UV    0xEF1000   // f32 [256]  u = ow*g_b
#define OFF_V2    0xEF1400   // f32 [256]  v2 = ph_w^T*th_b
#define OFF_W2    0xEF1800   // f32 [256]  w2 = th_w^T*ph_b
#define OFF_S2    0xEF1C00   // f32 s2 = ph_b.th_b
#define OFF_RV2   0xEF1C40   // f32 [4]  r.v2
#define OFF_CVEC  0xEF2000   // f32 [4][256]  U*r
#define OFF_GVEC  0xEF3000   // f32 [4][256]  (V^T r)/N + w2
#define OFF_QV    0xEF4000   // f32 [4][256]  per-channel constant of z
#define OFF_STATS 0xEF9000   // f32 [4][32][2] RAW (sum, sumsq) via atomics
#define OFF_ARR   0xEFA000   // u32 [256][16] per-block arrive flags (64B apart)
#define OFF_REL   0xEFE000   // u32 release flag
// ---------------------------------------------------------------------------

// ------------- coherent (agent-scope, MALL-backed) access helpers -----------
// Round-3 lesson: per-block agent fences (buffer_wbl2 + buffer_inv = whole-L2
// writeback/invalidate) cost ~22us per barrier. Instead of fencing, every
// cross-phase datum is written/read with relaxed agent-scope atomics (sc-bit
// write-through to MALL, L2-bypassing loads) so no fence is ever needed.
__device__ __forceinline__ bf16x8 ld16c(const __bf16* p)
{
  union { unsigned long long q[2]; bf16x8 v; } u;
  const unsigned long long* qp = (const unsigned long long*)p;
  u.q[0] = __hip_atomic_load(qp,     __ATOMIC_RELAXED, __HIP_MEMORY_SCOPE_AGENT);
  u.q[1] = __hip_atomic_load(qp + 1, __ATOMIC_RELAXED, __HIP_MEMORY_SCOPE_AGENT);
  return u.v;
}
__device__ __forceinline__ void stbf_c(__bf16* p, float v)
{
  union { __bf16 b; unsigned short u; } cv; cv.b = (__bf16)v;
  __hip_atomic_store((unsigned short*)p, cv.u, __ATOMIC_RELAXED,
                     __HIP_MEMORY_SCOPE_AGENT);
}
__device__ __forceinline__ float ldbf_c(const __bf16* p)
{
  union { unsigned short u; __bf16 b; } cv;
  cv.u = __hip_atomic_load((const unsigned short*)p, __ATOMIC_RELAXED,
                           __HIP_MEMORY_SCOPE_AGENT);
  return (float)cv.b;
}
__device__ __forceinline__ void stf_c(float* p, float v)
{
  __hip_atomic_store(p, v, __ATOMIC_RELAXED, __HIP_MEMORY_SCOPE_AGENT);
}
__device__ __forceinline__ float ldf_c(const float* p)
{
  return __hip_atomic_load(p, __ATOMIC_RELAXED, __HIP_MEMORY_SCOPE_AGENT);
}
template <bool C>
__device__ __forceinline__ bf16x8 gld(const __bf16* p)
{
  if constexpr (C) return ld16c(p);
  else return *(const bf16x8*)p;
}

// ---------------- prep: gather + weight cvt/transpose + bias matvecs --------
__global__ __launch_bounds__(256) void prep_k(
    const float* __restrict__ f0, const float* __restrict__ f1,
    const float* __restrict__ f2, const float* __restrict__ f3,
    const float* __restrict__ f4,
    const float* __restrict__ g_w, const float* __restrict__ ph_w,
    const float* __restrict__ th_w, const float* __restrict__ ow_w,
    const float* __restrict__ g_b, const float* __restrict__ ph_b,
    const float* __restrict__ th_b,
    char* __restrict__ ws)
{
  const int blk = blockIdx.x, t = threadIdx.x;
  __shared__ __attribute__((aligned(16))) union {
    __bf16 Lt[64][66];
    __bf16 T[64][72];
    float vec[256];
  } sm;

  if (blk < 256) {
    // ---- gather: bsf fp32 + bsfB bf16 (ch-major) + bsfT bf16 (sp-major) + rowsum partials
    float*  bsf   = (float*)(ws + OFF_BSF);
    __bf16* bsfT  = (__bf16*)(ws + OFF_BSFT);
    __bf16* bsfB  = (__bf16*)(ws + OFF_BSFB);
    float*  rpart = (float*)(ws + OFF_RPART);
    const int sblk = blk & 15, cblk = (blk >> 4) & 3, b = blk >> 6;
    const int c0 = cblk * 64, s0 = sblk * 64;
    const int spl = t & 63, sp = s0 + spl;
    const int y = sp >> 5, x = sp & 31;
#pragma unroll
    for (int i = 0; i < 16; ++i) {
      const int cl = (t >> 6) + i * 4;
      const int nc = b * 256 + c0 + cl;

      const float* p0 = f0 + (size_t)nc * 16384 + (y * 4) * 128 + x * 4;
      float4 r0 = *(const float4*)(p0);
      float4 r1 = *(const float4*)(p0 + 128);
      float4 r2 = *(const float4*)(p0 + 256);
      float4 r3 = *(const float4*)(p0 + 384);
      float a  = fmaxf(fmaxf(r0.x, r0.y), fmaxf(r0.z, r0.w));
      float bb = fmaxf(fmaxf(r1.x, r1.y), fmaxf(r1.z, r1.w));
      float c  = fmaxf(fmaxf(r2.x, r2.y), fmaxf(r2.z, r2.w));
      float d  = fmaxf(fmaxf(r3.x, r3.y), fmaxf(r3.z, r3.w));
      float m0v = fmaxf(fmaxf(a, bb), fmaxf(c, d));

      const float* p1 = f1 + (size_t)nc * 4096 + (y * 2) * 64 + x * 2;
      float2 s0v = *(const float2*)(p1);
      float2 s1v = *(const float2*)(p1 + 64);
      float m1v = fmaxf(fmaxf(s0v.x, s0v.y), fmaxf(s1v.x, s1v.y));

      float v2 = f2[(size_t)nc * 1024 + sp];
      float v3 = f3[(size_t)nc * 256 + (y >> 1) * 16 + (x >> 1)];
      float v4 = f4[(size_t)nc * 64  + (y >> 2) * 8  + (x >> 2)];
      float val = (m0v + m1v + v2 + v3 + v4) * 0.2f;
      bsf[(size_t)nc * 1024 + sp]  = val;
      bsfB[(size_t)nc * 1024 + sp] = (__bf16)val;
      sm.Lt[cl][spl] = (__bf16)val;
      float rs = val;
#pragma unroll
      for (int off = 32; off; off >>= 1) rs += __shfl_down(rs, off);
      if (spl == 0) rpart[sblk * 1024 + nc] = rs;
    }
    __syncthreads();
#pragma unroll
    for (int i = 0; i < 16; ++i) {
      int linear = t + i * 256;
      int spl2 = linear >> 6, cl2 = linear & 63;
      bsfT[((size_t)b * 1024 + s0 + spl2) * 256 + c0 + cl2] = sm.Lt[cl2][spl2];
    }
  } else if (blk < 304) {
    // ---- weight transposes (fp32 -> bf16): gwT/phT/thT, 64x64 tiles
    const int w = (blk - 256) >> 4, tl = (blk - 256) & 15;
    const float* src = (w == 0) ? g_w : (w == 1) ? ph_w : th_w;
    __bf16* dst = (__bf16*)(ws + ((w == 0) ? OFF_GWT : (w == 1) ? OFF_PHT : OFF_THT));
    const int ti = (tl >> 2) * 64, tj = (tl & 3) * 64;
#pragma unroll
    for (int i = 0; i < 4; ++i) {
      int idx = i * 256 + t;
      int r = idx >> 4, c4 = (idx & 15) << 2;
      float4 v = *(const float4*)&src[(size_t)(ti + r) * 256 + tj + c4];
      sm.T[c4 + 0][r] = (__bf16)v.x;
      sm.T[c4 + 1][r] = (__bf16)v.y;
      sm.T[c4 + 2][r] = (__bf16)v.z;
      sm.T[c4 + 3][r] = (__bf16)v.w;
    }
    __syncthreads();
#pragma unroll
    for (int i = 0; i < 2; ++i) {
      int idx = i * 256 + t;
      int aa = idx >> 3, cc = (idx & 7) << 3;
      bf16x8 o = *(const bf16x8*)&sm.T[aa][cc];
      *(bf16x8*)&dst[(size_t)(tj + aa) * 256 + ti + cc] = o;
    }
  } else if (blk < 308) {
    // ---- owB plain convert
    const int r0 = (blk - 304) * 64;
    __bf16* owB = (__bf16*)(ws + OFF_OWB);
#pragma unroll
    for (int i = 0; i < 8; ++i) {
      int lin = i * 2048 + t * 8;
      size_t gidx = (size_t)r0 * 256 + lin;
      float4 v0 = *(const float4*)&ow_w[gidx];
      float4 v1 = *(const float4*)&ow_w[gidx + 4];
      bf16x8 o;
      o[0] = (__bf16)v0.x; o[1] = (__bf16)v0.y; o[2] = (__bf16)v0.z; o[3] = (__bf16)v0.w;
      o[4] = (__bf16)v1.x; o[5] = (__bf16)v1.y; o[6] = (__bf16)v1.z; o[7] = (__bf16)v1.w;
      *(bf16x8*)&owB[gidx] = o;
    }
  } else if (blk == 308) {
    // ---- u = ow_w . g_b ; zero barrier flags + raw GN stats
    float* uv = (float*)(ws + OFF_UV);
    sm.vec[t] = g_b[t];
    __syncthreads();
    const int wv = t >> 6, l = t & 63;
    for (int rr = 0; rr < 64; ++rr) {
      int row = wv * 64 + rr;
      const float* p = ow_w + (size_t)row * 256;
      float pa = p[l] * sm.vec[l] + p[64 + l] * sm.vec[64 + l]
               + p[128 + l] * sm.vec[128 + l] + p[192 + l] * sm.vec[192 + l];
#pragma unroll
      for (int off = 32; off; off >>= 1) pa += __shfl_down(pa, off);
      if (l == 0) uv[row] = pa;
    }
    unsigned* arr = (unsigned*)(ws + OFF_ARR);
#pragma unroll
    for (int i = 0; i < 16; ++i) arr[t * 16 + i] = 0u;
    if (t == 0) *(unsigned*)(ws + OFF_REL) = 0u;
    ((float*)(ws + OFF_STATS))[t] = 0.f;
  } else if (blk == 309) {
    // ---- v2 = ph_w^T . th_b (column dot, coalesced) ; s2 = ph_b.th_b
    float* v2 = (float*)(ws + OFF_V2);
    float* s2 = (float*)(ws + OFF_S2);
    float acc = 0.f;
#pragma unroll 8
    for (int c = 0; c < 256; ++c) acc += ph_w[(size_t)c * 256 + t] * th_b[c];
    v2[t] = acc;
    if (t < 64) {
      float pa = ph_b[t] * th_b[t] + ph_b[64 + t] * th_b[64 + t]
               + ph_b[128 + t] * th_b[128 + t] + ph_b[192 + t] * th_b[192 + t];
#pragma unroll
      for (int off = 32; off; off >>= 1) pa += __shfl_down(pa, off);
      if (t == 0) s2[0] = pa;
    }
  } else {
    // ---- w2 = th_w^T . ph_b
    float* w2 = (float*)(ws + OFF_W2);
    float acc = 0.f;
#pragma unroll 8
    for (int c = 0; c < 256; ++c) acc += th_w[(size_t)c * 256 + t] * ph_b[c];
    w2[t] = acc;
  }
}

// ---------------- GEMM accumulate core (64x64 tile, 4 waves, dbuf) ----------
// AC/BC: load A/B operand through coherent (agent-scope) path.
template <bool AC, bool BC>
__device__ __forceinline__ void gemm_acc(
    const __bf16* __restrict__ A, const __bf16* __restrict__ B,
    const int K, const int m0, const int n0,
    __bf16 (*Al)[64][72], __bf16 (*Bl)[64][72],
    f32x4 acc[2][2])
{
  const int t = threadIdx.x;
  const int lane = t & 63, wv = t >> 6;
  const int wm = (wv & 1) * 32, wn = (wv >> 1) * 32;
  const int fr = lane & 15, lk = (lane >> 4) * 8;
  const int sr = t >> 2, sk = (t & 3) * 16;

  const __bf16* Ar = A + (size_t)(m0 + sr) * K + sk;
  const __bf16* Br = B + (size_t)(n0 + sr) * K + sk;

  bf16x8 ra0 = gld<AC>(Ar);
  bf16x8 ra1 = gld<AC>(Ar + 8);
  bf16x8 rb0 = gld<BC>(Br);
  bf16x8 rb1 = gld<BC>(Br + 8);

  const int nIter = K >> 6;
  int p = 0;
  for (int it = 0; it < nIter; ++it) {
    *(bf16x8*)&Al[p][sr][sk]     = ra0;
    *(bf16x8*)&Al[p][sr][sk + 8] = ra1;
    *(bf16x8*)&Bl[p][sr][sk]     = rb0;
    *(bf16x8*)&Bl[p][sr][sk + 8] = rb1;
    __syncthreads();
    if (it + 1 < nIter) {
      const __bf16* An = Ar + (size_t)(it + 1) * 64;
      const __bf16* Bn = Br + (size_t)(it + 1) * 64;
      ra0 = gld<AC>(An);
      ra1 = gld<AC>(An + 8);
      rb0 = gld<BC>(Bn);
      rb1 = gld<BC>(Bn + 8);
    }
#pragma unroll
    for (int kk = 0; kk < 64; kk += 32) {
      bf16x8 a0 = *(const bf16x8*)&Al[p][wm + fr][kk + lk];
      bf16x8 a1 = *(const bf16x8*)&Al[p][wm + 16 + fr][kk + lk];
      bf16x8 b0 = *(const bf16x8*)&Bl[p][wn + fr][kk + lk];
      bf16x8 b1 = *(const bf16x8*)&Bl[p][wn + 16 + fr][kk + lk];
      acc[0][0] = __builtin_amdgcn_mfma_f32_16x16x32_bf16(a0, b0, acc[0][0], 0, 0, 0);
      acc[0][1] = __builtin_amdgcn_mfma_f32_16x16x32_bf16(a0, b1, acc[0][1], 0, 0, 0);
      acc[1][0] = __builtin_amdgcn_mfma_f32_16x16x32_bf16(a1, b0, acc[1][0], 0, 0, 0);
      acc[1][1] = __builtin_amdgcn_mfma_f32_16x16x32_bf16(a1, b1, acc[1][1], 0, 0, 0);
    }
    __syncthreads();
    p ^= 1;
  }
}

// coherent bf16 tile store
__device__ __forceinline__ void store_bf16_c(
    __bf16* dst, int ldst, const f32x4 acc[2][2],
    int m0, int n0, int wm, int wn, int rbase, int fr)
{
#pragma unroll
  for (int i = 0; i < 2; ++i)
#pragma unroll
    for (int r = 0; r < 4; ++r) {
      int m = m0 + wm + i * 16 + rbase + r;
#pragma unroll
      for (int j = 0; j < 2; ++j) {
        int n = n0 + wn + j * 16 + fr;
        stbf_c(&dst[(size_t)m * ldst + n], acc[i][j][r]);
      }
    }
}

// ---------------- software grid barrier, v4 (fence-free) --------------------
// All cross-phase data moves through agent-scope (MALL-coherent) accesses, so
// the barrier needs NO cache maintenance: __syncthreads drains each wave's
// vmcnt (coherent stores complete at the MALL), then arrival/release are
// relaxed agent atomics. Block 0's 256 threads poll 256 distinct lines;
// other blocks' thread 0 polls one release flag with s_sleep backoff.
__device__ __forceinline__ void gsync(char* __restrict__ ws, int p)
{
  unsigned* arr = (unsigned*)(ws + OFF_ARR);
  unsigned* rel = (unsigned*)(ws + OFF_REL);
  const int t = threadIdx.x;
  __syncthreads();                 // drains vmcnt/lgkm for every wave
  if (blockIdx.x == 0) {
    if (t > 0) {
      while (__hip_atomic_load(&arr[t * 16], __ATOMIC_RELAXED,
                               __HIP_MEMORY_SCOPE_AGENT) < (unsigned)p)
        __builtin_amdgcn_s_sleep(2);
    }
    __syncthreads();
    if (t == 0)
      __hip_atomic_store(rel, (unsigned)p, __ATOMIC_RELAXED,
                         __HIP_MEMORY_SCOPE_AGENT);
    __syncthreads();
  } else {
    if (t == 0) {
      __hip_atomic_store(&arr[blockIdx.x * 16], (unsigned)p, __ATOMIC_RELAXED,
                         __HIP_MEMORY_SCOPE_AGENT);
      while (__hip_atomic_load(rel, __ATOMIC_RELAXED,
                               __HIP_MEMORY_SCOPE_AGENT) < (unsigned)p)
        __builtin_amdgcn_s_sleep(8);
    }
    __syncthreads();
  }
}

// ---------------- persistent middle kernel ----------------------------------
// P0: S = bsf.bsf^T (hi/lo bf16) ; U = ow*g_w ; V = ph_w^T*th_w ; r finalize
// P1: T0 = U*S (split-compensated) ; cvec = U*r ; gvec = (V^T r)/N + w2 ; rv2
// P2: Mth = T0*V/N + rank-1 bias terms ; qv = per-channel const of z
// P3: z = Mth*bsf + qv ; GN raw stats via global atomics
// All cross-phase tensors use agent-coherent accesses (no fences anywhere).
__global__ __launch_bounds__(256) void middle_k(char* __restrict__ ws,
                                                const float* __restrict__ ow_b)
{
  const int blk = blockIdx.x, t = threadIdx.x;
  __shared__ __attribute__((aligned(16))) __bf16 Al[2][64][72];
  __shared__ __attribute__((aligned(16))) __bf16 Bl[2][64][72];
  float* shf = (float*)(&Al[0][0][0]);

  const int lane = t & 63, wv = t >> 6;
  const int wm = (wv & 1) * 32, wn = (wv >> 1) * 32;
  const int fr = lane & 15;
  const int rbase = (lane >> 4) * 4;

  const __bf16* bsfB = (const __bf16*)(ws + OFF_BSFB);
  const __bf16* bsfT = (const __bf16*)(ws + OFF_BSFT);
  __bf16* SBh  = (__bf16*)(ws + OFF_SBH);
  __bf16* SBl  = (__bf16*)(ws + OFF_SBL);
  __bf16* T0B  = (__bf16*)(ws + OFF_T0);
  __bf16* MthB = (__bf16*)(ws + OFF_MTH);
  const __bf16* owB = (const __bf16*)(ws + OFF_OWB);
  const __bf16* gwT = (const __bf16*)(ws + OFF_GWT);
  const __bf16* phT = (const __bf16*)(ws + OFF_PHT);
  const __bf16* thT = (const __bf16*)(ws + OFF_THT);
  __bf16* UB  = (__bf16*)(ws + OFF_UB);
  __bf16* VB  = (__bf16*)(ws + OFF_VB);
  __bf16* VTB = (__bf16*)(ws + OFF_VTB);
  float* Z  = (float*)(ws + OFF_Z);
  float* Rr = (float*)(ws + OFF_R);
  const float* rpart = (const float*)(ws + OFF_RPART);
  const float* uv  = (const float*)(ws + OFF_UV);
  const float* v2f = (const float*)(ws + OFF_V2);
  const float* w2f = (const float*)(ws + OFF_W2);
  const float* s2f = (const float*)(ws + OFF_S2);
  float* rv2  = (float*)(ws + OFF_RV2);
  float* cvec = (float*)(ws + OFF_CVEC);
  float* gvec = (float*)(ws + OFF_GVEC);
  float* qv   = (float*)(ws + OFF_QV);
  float* SRAW = (float*)(ws + OFF_STATS);

  // ---------------- P0 ----------------
  if (blk < 64) {
    const int b = blk >> 4, tl = blk & 15;
    const int m0 = (tl >> 2) * 64, n0 = (tl & 3) * 64;
    f32x4 acc[2][2];
#pragma unroll
    for (int i = 0; i < 2; ++i)
#pragma unroll
      for (int j = 0; j < 2; ++j) acc[i][j] = (f32x4){0.f, 0.f, 0.f, 0.f};
    gemm_acc<false, false>(bsfB + (size_t)b * 262144, bsfB + (size_t)b * 262144,
                           1024, m0, n0, Al, Bl, acc);
    __bf16* oh = SBh + (size_t)b * 65536;
    __bf16* ol = SBl + (size_t)b * 65536;
#pragma unroll
    for (int i = 0; i < 2; ++i)
#pragma unroll
      for (int r = 0; r < 4; ++r) {
        int m = m0 + wm + i * 16 + rbase + r;
#pragma unroll
        for (int j = 0; j < 2; ++j) {
          int n = n0 + wn + j * 16 + fr;
          float v = acc[i][j][r];
          float hf = (float)(__bf16)v;
          stbf_c(&oh[(size_t)m * 256 + n], v);
          stbf_c(&ol[(size_t)m * 256 + n], v - hf);
        }
      }
  } else if (blk < 80) {
    const int tl = blk - 64;
    const int m0 = (tl >> 2) * 64, n0 = (tl & 3) * 64;
    f32x4 acc[2][2];
#pragma unroll
    for (int i = 0; i < 2; ++i)
#pragma unroll
      for (int j = 0; j < 2; ++j) acc[i][j] = (f32x4){0.f, 0.f, 0.f, 0.f};
    gemm_acc<false, false>(owB, gwT, 256, m0, n0, Al, Bl, acc);
    store_bf16_c(UB, 256, acc, m0, n0, wm, wn, rbase, fr);
  } else if (blk < 96) {
    const int tl = blk - 80;
    const int m0 = (tl >> 2) * 64, n0 = (tl & 3) * 64;
    f32x4 acc[2][2];
#pragma unroll
    for (int i = 0; i < 2; ++i)
#pragma unroll
      for (int j = 0; j < 2; ++j) acc[i][j] = (f32x4){0.f, 0.f, 0.f, 0.f};
    gemm_acc<false, false>(phT, thT, 256, m0, n0, Al, Bl, acc);
#pragma unroll
    for (int i = 0; i < 2; ++i)
#pragma unroll
      for (int r = 0; r < 4; ++r) {
        int m = m0 + wm + i * 16 + rbase + r;
#pragma unroll
        for (int j = 0; j < 2; ++j) {
          int n = n0 + wn + j * 16 + fr;
          float v = acc[i][j][r];
          stbf_c(&VB[(size_t)m * 256 + n], v);
          stbf_c(&VTB[(size_t)n * 256 + m], v);
        }
      }
  } else if (blk == 96) {
#pragma unroll
    for (int j2 = 0; j2 < 4; ++j2) {
      int idx = t + j2 * 256;
      float s = 0.f;
#pragma unroll
      for (int k = 0; k < 16; ++k) s += rpart[k * 1024 + idx];
      stf_c(&Rr[idx], s);
    }
  }
  gsync(ws, 1);

  // ---------------- P1 ----------------
  if (blk < 64) {
    const int b = blk >> 4, tl = blk & 15;
    const int m0 = (tl >> 2) * 64, n0 = (tl & 3) * 64;
    f32x4 acc[2][2];
#pragma unroll
    for (int i = 0; i < 2; ++i)
#pragma unroll
      for (int j = 0; j < 2; ++j) acc[i][j] = (f32x4){0.f, 0.f, 0.f, 0.f};
    gemm_acc<true, true>(UB, SBh + (size_t)b * 65536, 256, m0, n0, Al, Bl, acc);
    gemm_acc<true, true>(UB, SBl + (size_t)b * 65536, 256, m0, n0, Al, Bl, acc);
    store_bf16_c(T0B + (size_t)b * 65536, 256, acc, m0, n0, wm, wn, rbase, fr);
  } else if (blk < 80) {
    const int q = blk - 64;
    const int b = q >> 2, r0 = (q & 3) * 64;
    shf[t] = ldf_c(&Rr[b * 256 + t]);
    __syncthreads();
    for (int rr = 0; rr < 16; ++rr) {
      int row = r0 + wv * 16 + rr;
      const __bf16* p = UB + (size_t)row * 256;
      float pa = ldbf_c(p + lane) * shf[lane] + ldbf_c(p + 64 + lane) * shf[64 + lane]
               + ldbf_c(p + 128 + lane) * shf[128 + lane] + ldbf_c(p + 192 + lane) * shf[192 + lane];
#pragma unroll
      for (int off = 32; off; off >>= 1) pa += __shfl_down(pa, off);
      if (lane == 0) stf_c(&cvec[b * 256 + row], pa);
    }
  } else if (blk < 84) {
    const int b = blk - 80;
    shf[t] = ldf_c(&Rr[b * 256 + t]);
    __syncthreads();
    float acc2 = 0.f;
#pragma unroll 8
    for (int c2 = 0; c2 < 256; ++c2) acc2 += ldbf_c(&VB[(size_t)c2 * 256 + t]) * shf[c2];
    stf_c(&gvec[b * 256 + t], acc2 * (1.f / 1024.f) + w2f[t]);
  } else if (blk == 84) {
    float pa = ldf_c(&Rr[wv * 256 + lane]) * v2f[lane]
             + ldf_c(&Rr[wv * 256 + 64 + lane]) * v2f[64 + lane]
             + ldf_c(&Rr[wv * 256 + 128 + lane]) * v2f[128 + lane]
             + ldf_c(&Rr[wv * 256 + 192 + lane]) * v2f[192 + lane];
#pragma unroll
    for (int off = 32; off; off >>= 1) pa += __shfl_down(pa, off);
    if (lane == 0) stf_c(&rv2[wv], pa);
  }
  gsync(ws, 2);

  // ---------------- P2 ----------------
  if (blk < 64) {
    const int b = blk >> 4, tl = blk & 15;
    const int m0 = (tl >> 2) * 64, n0 = (tl & 3) * 64;
    f32x4 acc[2][2];
#pragma unroll
    for (int i = 0; i < 2; ++i)
#pragma unroll
      for (int j = 0; j < 2; ++j) acc[i][j] = (f32x4){0.f, 0.f, 0.f, 0.f};
    gemm_acc<true, true>(T0B + (size_t)b * 65536, VTB, 256, m0, n0, Al, Bl, acc);
    const float s1024 = 1.f / 1024.f;
    __bf16* od = MthB + (size_t)b * 65536;
#pragma unroll
    for (int i = 0; i < 2; ++i)
#pragma unroll
      for (int r = 0; r < 4; ++r) {
        int m = m0 + wm + i * 16 + rbase + r;
        float um = uv[m], cv = ldf_c(&cvec[b * 256 + m]);
#pragma unroll
        for (int j = 0; j < 2; ++j) {
          int n = n0 + wn + j * 16 + fr;
          float val = acc[i][j][r] * s1024 + um * ldf_c(&gvec[b * 256 + n])
                    + cv * w2f[n] * s1024;
          stbf_c(&od[(size_t)m * 256 + n], val);
        }
      }
  } else if (blk < 68) {
    const int b = blk - 64;
    shf[t] = v2f[t];
    __syncthreads();
    const float rvb = ldf_c(&rv2[b]), s2v = s2f[0];
    for (int rr = 0; rr < 64; ++rr) {
      int row = wv * 64 + rr;
      const __bf16* p = T0B + (size_t)b * 65536 + (size_t)row * 256;
      float pa = ldbf_c(p + lane) * shf[lane] + ldbf_c(p + 64 + lane) * shf[64 + lane]
               + ldbf_c(p + 128 + lane) * shf[128 + lane] + ldbf_c(p + 192 + lane) * shf[192 + lane];
#pragma unroll
      for (int off = 32; off; off >>= 1) pa += __shfl_down(pa, off);
      if (lane == 0)
        stf_c(&qv[b * 256 + row],
              pa * (1.f / 1024.f)
              + uv[row] * (rvb * (1.f / 1024.f) + s2v)
              + ldf_c(&cvec[b * 256 + row]) * s2v * (1.f / 1024.f)
              + ow_b[row]);
    }
  }
  gsync(ws, 3);

  // ---------------- P3: z = Mth*bsf + qv, GN raw stats via atomics ----------
  {
    const int b = blk >> 6, t6 = blk & 63;
    const int mt = t6 >> 4, nt = t6 & 15;
    const int m0 = mt * 64, n0 = nt * 64;
    (void)nt;
    f32x4 acc[2][2];
#pragma unroll
    for (int i = 0; i < 2; ++i)
#pragma unroll
      for (int j = 0; j < 2; ++j) acc[i][j] = (f32x4){0.f, 0.f, 0.f, 0.f};
    gemm_acc<true, false>(MthB + (size_t)b * 65536, bsfT + (size_t)b * 262144,
                          256, m0, n0, Al, Bl, acc);

    float gs[2] = {0.f, 0.f}, gq[2] = {0.f, 0.f};
    int gidx[2];
    float* zb = Z + (size_t)b * 262144;
#pragma unroll
    for (int i = 0; i < 2; ++i) {
      gidx[i] = (wm + i * 16 + rbase) >> 3;
#pragma unroll
      for (int r = 0; r < 4; ++r) {
        int m = m0 + wm + i * 16 + rbase + r;
        float qm = ldf_c(&qv[b * 256 + m]);
#pragma unroll
        for (int j = 0; j < 2; ++j) {
          int n = n0 + wn + j * 16 + fr;
          float v = acc[i][j][r] + qm;
          zb[(size_t)m * 1024 + n] = v;
          gs[i] += v;
          gq[i] += v * v;
        }
      }
    }
    __syncthreads();
    if (t < 16) shf[t] = 0.f;
    __syncthreads();
#pragma unroll
    for (int i = 0; i < 2; ++i) {
      atomicAdd(&shf[gidx[i] * 2], gs[i]);
      atomicAdd(&shf[gidx[i] * 2 + 1], gq[i]);
    }
    __syncthreads();
    if (t < 16) {
      int g = mt * 8 + (t >> 1);
      atomicAdd(&SRAW[(b * 32 + g) * 2 + (t & 1)], shf[t]);
    }
  }
}

// ---------------- fused GN + residual scatter (float4) ----------------------
__device__ __forceinline__ float4 gmix(float4 bz, float4 zz, float a, float c)
{
  float4 r;
  r.x = bz.x + zz.x * a + c;
  r.y = bz.y + zz.y * a + c;
  r.z = bz.z + zz.z * a + c;
  r.w = bz.w + zz.w * a + c;
  return r;
}
__device__ __forceinline__ float max4(float4 v)
{ return fmaxf(fmaxf(v.x, v.y), fmaxf(v.z, v.w)); }

// raw (sum, sumsq) -> (a = inv*gamma, c0 = beta - mean*a)
__device__ __forceinline__ void gn_coeff(const float2* __restrict__ ST,
                                         const float* __restrict__ gamma,
                                         const float* __restrict__ beta,
                                         int b, int ch, float& a, float& c0)
{
  float2 sq = ST[b * 32 + (ch >> 3)];
  float mean = sq.x * (1.0f / 8192.0f);
  float var  = sq.y * (1.0f / 8192.0f) - mean * mean;
  float inv  = rsqrtf(var + 1e-5f);
  a  = inv * gamma[ch];
  c0 = beta[ch] - mean * a;
}

__global__ __launch_bounds__(256) void scat_k(
    const char* __restrict__ ws,
    const float* __restrict__ f0, const float* __restrict__ f1,
    const float* __restrict__ f2, const float* __restrict__ f3,
    const float* __restrict__ f4,
    const float* __restrict__ gamma, const float* __restrict__ beta,
    float* __restrict__ out)
{
  const float* Z = (const float*)(ws + OFF_Z);
  const float* BSF = (const float*)(ws + OFF_BSF);
  const float2* ST = (const float2*)(ws + OFF_STATS);
  const int i4 = blockIdx.x * 256 + threadIdx.x;

  if (i4 < 4194304) {                       // f0: 128x128, upsample x4
    const int l = i4 << 2;
    const int x = l & 127, yy = (l >> 7) & 127, nc = l >> 14;
    const int ch = nc & 255, b = nc >> 8;
    float a, c0; gn_coeff(ST, gamma, beta, b, ch, a, c0);
    size_t base = (size_t)nc * 1024 + ((yy >> 2) << 5) + (x >> 2);
    float v = BSF[base] + Z[base] * a + c0;
    float4 f = ((const float4*)f0)[i4];
    float4 o; o.x = f.x + v; o.y = f.y + v; o.z = f.z + v; o.w = f.w + v;
    ((float4*)out)[i4] = o;
  } else if (i4 < 5242880) {                // f1: 64x64, upsample x2
    const int l4 = i4 - 4194304;
    const int l = l4 << 2;
    const int x = l & 63, yy = (l >> 6) & 63, nc = l >> 12;
    const int ch = nc & 255, b = nc >> 8;
    float a, c0; gn_coeff(ST, gamma, beta, b, ch, a, c0);
    size_t base = (size_t)nc * 1024 + ((yy >> 1) << 5) + (x >> 1);
    float v0 = BSF[base] + Z[base] * a + c0;
    float v1 = BSF[base + 1] + Z[base + 1] * a + c0;
    float4 f = ((const float4*)f1)[l4];
    float4 o; o.x = f.x + v0; o.y = f.y + v0; o.z = f.z + v1; o.w = f.w + v1;
    ((float4*)out)[i4] = o;
  } else if (i4 < 5505024) {                // f2: 32x32, identity
    const int l4 = i4 - 5242880;
    const int l = l4 << 2;
    const int nc = l >> 10, e = l & 1023;
    const int ch = nc & 255, b = nc >> 8;
    float a, c0; gn_coeff(ST, gamma, beta, b, ch, a, c0);
    size_t base = (size_t)nc * 1024 + e;
    float4 z4 = *(const float4*)&Z[base];
    float4 b4 = *(const float4*)&BSF[base];
    float4 v = gmix(b4, z4, a, c0);
    float4 f = ((const float4*)f2)[l4];
    float4 o; o.x = f.x + v.x; o.y = f.y + v.y; o.z = f.z + v.z; o.w = f.w + v.w;
    ((float4*)out)[i4] = o;
  } else if (i4 < 5570560) {                // f3: 16x16, maxpool 2x2
    const int l4 = i4 - 5505024;
    const int l = l4 << 2;
    const int x = l & 15, yy = (l >> 4) & 15, nc = l >> 8;
    const int ch = nc & 255, b = nc >> 8;
    float a, c0; gn_coeff(ST, gamma, beta, b, ch, a, c0);
    size_t base = (size_t)nc * 1024;
    const int p0 = (yy * 2) * 32 + (x * 2);
    float4 r0a = gmix(*(const float4*)&BSF[base + p0],      *(const float4*)&Z[base + p0],      a, c0);
    float4 r0b = gmix(*(const float4*)&BSF[base + p0 + 4],  *(const float4*)&Z[base + p0 + 4],  a, c0);
    float4 r1a = gmix(*(const float4*)&BSF[base + p0 + 32], *(const float4*)&Z[base + p0 + 32], a, c0);
    float4 r1b = gmix(*(const float4*)&BSF[base + p0 + 36], *(const float4*)&Z[base + p0 + 36], a, c0);
    float4 f = ((const float4*)f3)[l4];
    float4 o;
    o.x = f.x + fmaxf(fmaxf(r0a.x, r0a.y), fmaxf(r1a.x, r1a.y));
    o.y = f.y + fmaxf(fmaxf(r0a.z, r0a.w), fmaxf(r1a.z, r1a.w));
    o.z = f.z + fmaxf(fmaxf(r0b.x, r0b.y), fmaxf(r1b.x, r1b.y));
    o.w = f.w + fmaxf(fmaxf(r0b.z, r0b.w), fmaxf(r1b.z, r1b.w));
    ((float4*)out)[i4] = o;
  } else {                                   // f4: 8x8, maxpool 4x4
    const int l4 = i4 - 5570560;
    const int l = l4 << 2;
    const int x = l & 7, yy = (l >> 3) & 7, nc = l >> 6;
    const int ch = nc & 255, b = nc >> 8;
    float a, c0; gn_coeff(ST, gamma, beta, b, ch, a, c0);
    size_t base = (size_t)nc * 1024;
    float4 mx = {-3.4e38f, -3.4e38f, -3.4e38f, -3.4e38f};
#pragma unroll
    for (int r = 0; r < 4; ++r) {
      const float* zp = &Z[base + (size_t)(yy * 4 + r) * 32 + x * 4];
      const float* bp = &BSF[base + (size_t)(yy * 4 + r) * 32 + x * 4];
      float4 q0 = gmix(*(const float4*)(bp),      *(const float4*)(zp),      a, c0);
      float4 q1 = gmix(*(const float4*)(bp + 4),  *(const float4*)(zp + 4),  a, c0);
      float4 q2 = gmix(*(const float4*)(bp + 8),  *(const float4*)(zp + 8),  a, c0);
      float4 q3 = gmix(*(const float4*)(bp + 12), *(const float4*)(zp + 12), a, c0);
      mx.x = fmaxf(mx.x, max4(q0));
      mx.y = fmaxf(mx.y, max4(q1));
      mx.z = fmaxf(mx.z, max4(q2));
      mx.w = fmaxf(mx.w, max4(q3));
    }
    float4 f = ((const float4*)f4)[l4];
    float4 o; o.x = f.x + mx.x; o.y = f.y + mx.y; o.z = f.z + mx.z; o.w = f.w + mx.w;
    ((float4*)out)[i4] = o;
  }
}

// ---------------------------------------------------------------------------
extern "C" void kernel_launch(void* const* d_in, const int* in_sizes, int n_in,
                              void* d_out, int out_size, void* d_ws, size_t ws_size,
                              hipStream_t stream)
{
  (void)in_sizes; (void)n_in; (void)out_size; (void)ws_size;
  const float* f0   = (const float*)d_in[0];
  const float* f1   = (const float*)d_in[1];
  const float* f2   = (const float*)d_in[2];
  const float* f3   = (const float*)d_in[3];
  const float* f4   = (const float*)d_in[4];
  const float* g_w  = (const float*)d_in[5];
  const float* g_b  = (const float*)d_in[6];
  const float* th_w = (const float*)d_in[7];
  const float* th_b = (const float*)d_in[8];
  const float* ph_w = (const float*)d_in[9];
  const float* ph_b = (const float*)d_in[10];
  const float* ow_w = (const float*)d_in[11];
  const float* ow_b = (const float*)d_in[12];
  const float* gn_g = (const float*)d_in[13];
  const float* gn_b = (const float*)d_in[14];
  char* ws = (char*)d_ws;

  // 1) gather + weight prep (independent roles, one launch)
  prep_k<<<311, 256, 0, stream>>>(f0, f1, f2, f3, f4,
                                  g_w, ph_w, th_w, ow_w,
                                  g_b, ph_b, th_b, ws);
  // 2) persistent middle: S -> T0 -> Mth -> z(+GN stats), fence-free barriers
  middle_k<<<256, 256, 0, stream>>>(ws, ow_b);
  // 3) fused GN-normalize + residual scatter (stats finalized inline)
  scat_k<<<21824, 256, 0, stream>>>(ws, f0, f1, f2, f3, f4, gn_g, gn_b,
                                    (float*)d_out);
}